// Round 8
// baseline (1165.663 us; speedup 1.0000x reference)
//
#include <hip/hip_runtime.h>
#include <hip/hip_cooperative_groups.h>
#include <hip/hip_bf16.h>
#include <math.h>

namespace cg = cooperative_groups;

#define N_NODES 100000
#define N_EDGES 1600000
#define F 128
#define OUT_C 64
#define NUM_CLASSES 40
#define BN_EPS 1e-5f

#define NBUCK 782   // ceil(100000/128) buckets of 128 destination nodes
#define BCAP 4096   // per-bucket edge capacity

// fallback (multi-kernel) fill constants — R6 proven
#define FILL_BLOCKS 512
#define EPB ((N_EDGES + FILL_BLOCKS - 1) / FILL_BLOCKS)  // 3125
#define FILL_ITERS 13  // ceil(EPB/256)

// mega (cooperative) constants: 256 blocks = 1 block/CU guaranteed co-resident
#define GB 256
#define BT 512
#define MEPB ((N_EDGES + GB - 1) / GB)    // 6250
#define MFITERS ((MEPB + BT - 1) / BT)    // 13

typedef __hip_bfloat16 bf16;
typedef __attribute__((ext_vector_type(8))) short bf16x8;
typedef __attribute__((ext_vector_type(4))) float f32x4;

// ---- fp32 param block offsets ----
#define PW1 0
#define PB1 16384
#define PW2 16512
#define PB2 32896
#define PGAMMA 33024
#define PBETA 33152
#define PMEAN 33280
#define PVAR 33408
#define PCLSW 33536
#define PCLSB 41728
#define PSIMW 41792
#define PSIMB 46912
#define PHOMW 46952
#define PHOMB 47080
#define PENTW 47081
#define PENTB 47209
#define PRAW_TOTAL 47210
#define PFW 47232
#define PFB 63616
#define PTOTAL 63744

struct ParamSegs {
    const void* src[16];
    int dst[16];
};

__device__ __forceinline__ float uasf(unsigned u) { return __uint_as_float(u); }
__device__ __forceinline__ unsigned f2bu(float f) {
    bf16 h = __float2bfloat16(f);
    return (unsigned)*(unsigned short*)&h;
}
__device__ __forceinline__ int load_edge(const int* __restrict__ ei, int which, int i, int i64) {
    size_t elem = (size_t)which * N_EDGES + (size_t)i;
    return i64 ? ei[elem * 2] : ei[elem];
}
__device__ __forceinline__ float headw(const float* __restrict__ p, int j, int c) {
    if (c < OUT_C) return p[PCLSW + j * OUT_C + c];
    if (c < OUT_C + NUM_CLASSES) return p[PSIMW + j * NUM_CLASSES + (c - OUT_C)];
    if (c == 104) return p[PHOMW + j];
    if (c == 105) return p[PENTW + j];
    return 0.f;
}

#define ACC8(u)                                \
    do {                                       \
        a[0] += uasf((u).x << 16);             \
        a[1] += uasf((u).x & 0xFFFF0000u);     \
        a[2] += uasf((u).y << 16);             \
        a[3] += uasf((u).y & 0xFFFF0000u);     \
        a[4] += uasf((u).z << 16);             \
        a[5] += uasf((u).z & 0xFFFF0000u);     \
        a[6] += uasf((u).w << 16);             \
        a[7] += uasf((u).w & 0xFFFF0000u);     \
    } while (0)

// ---- shared device helpers: agg (half-split, XCD-claimed) and gemm phases ----
__device__ void agg_phase(const unsigned short* __restrict__ IN16,
                          unsigned short* __restrict__ OUT16,
                          const int* __restrict__ srcBuck, const int* __restrict__ doffG,
                          const int* __restrict__ dcntG, const float* __restrict__ dinv,
                          int* __restrict__ wpair, int t, int* __restrict__ sIdx,
                          int* __restrict__ sdoff, int* __restrict__ sdcnt,
                          volatile int* __restrict__ sCtl, int nthreads) {
    int g8 = t >> 3;
    int lo8 = (t & 7) << 3;
    int ng = nthreads >> 3;
    for (;;) {
        if (t == 0) {
            unsigned xcc;
            asm volatile("s_getreg_b32 %0, hwreg(HW_REG_XCC_ID)" : "=s"(xcc));
            int half = (xcc >> 2) & 1;
            int idx = atomicAdd(&wpair[half], 1);
            if (idx >= NBUCK) {
                half ^= 1;
                idx = atomicAdd(&wpair[half], 1);
            }
            sCtl[0] = (idx < NBUCK) ? idx : -1;
            sCtl[1] = half;
        }
        __syncthreads();
        int b = sCtl[0], h = sCtl[1];
        if (b < 0) break;
        if (t < 128) {
            sdoff[t] = doffG[(b << 7) + t];
            sdcnt[t] = dcntG[(b << 7) + t];
        }
        __syncthreads();
        int cnt = sdoff[127] + sdcnt[127];
        for (int i = t; i < cnt; i += nthreads) sIdx[i] = srcBuck[b * BCAP + i];
        __syncthreads();
        int hoff = h * 64 + lo8;
        int base = b << 7;
        for (int d = g8; d < 128; d += ng) {
            int n = base + d;
            if (n >= N_NODES) break;
            float a[8] = {0.f, 0.f, 0.f, 0.f, 0.f, 0.f, 0.f, 0.f};
            {
                uint4 u = *(const uint4*)(IN16 + ((size_t)n << 7) + hoff);
                ACC8(u);
            }
            int o = sdoff[d], k = sdcnt[d];
            int j = 0;
            for (; j + 8 <= k; j += 8) {
                int s0 = sIdx[o + j + 0], s1 = sIdx[o + j + 1];
                int s2 = sIdx[o + j + 2], s3 = sIdx[o + j + 3];
                int s4 = sIdx[o + j + 4], s5 = sIdx[o + j + 5];
                int s6 = sIdx[o + j + 6], s7 = sIdx[o + j + 7];
                uint4 u0 = *(const uint4*)(IN16 + ((size_t)s0 << 7) + hoff);
                uint4 u1 = *(const uint4*)(IN16 + ((size_t)s1 << 7) + hoff);
                uint4 u2 = *(const uint4*)(IN16 + ((size_t)s2 << 7) + hoff);
                uint4 u3 = *(const uint4*)(IN16 + ((size_t)s3 << 7) + hoff);
                uint4 u4 = *(const uint4*)(IN16 + ((size_t)s4 << 7) + hoff);
                uint4 u5 = *(const uint4*)(IN16 + ((size_t)s5 << 7) + hoff);
                uint4 u6 = *(const uint4*)(IN16 + ((size_t)s6 << 7) + hoff);
                uint4 u7 = *(const uint4*)(IN16 + ((size_t)s7 << 7) + hoff);
                ACC8(u0);
                ACC8(u1);
                ACC8(u2);
                ACC8(u3);
                ACC8(u4);
                ACC8(u5);
                ACC8(u6);
                ACC8(u7);
            }
            for (; j + 4 <= k; j += 4) {
                int s0 = sIdx[o + j + 0], s1 = sIdx[o + j + 1];
                int s2 = sIdx[o + j + 2], s3 = sIdx[o + j + 3];
                uint4 u0 = *(const uint4*)(IN16 + ((size_t)s0 << 7) + hoff);
                uint4 u1 = *(const uint4*)(IN16 + ((size_t)s1 << 7) + hoff);
                uint4 u2 = *(const uint4*)(IN16 + ((size_t)s2 << 7) + hoff);
                uint4 u3 = *(const uint4*)(IN16 + ((size_t)s3 << 7) + hoff);
                ACC8(u0);
                ACC8(u1);
                ACC8(u2);
                ACC8(u3);
            }
            for (; j < k; j++) {
                int s0 = sIdx[o + j];
                uint4 u0 = *(const uint4*)(IN16 + ((size_t)s0 << 7) + hoff);
                ACC8(u0);
            }
            float dn = dinv[n];
            uint4 pk;
            pk.x = f2bu(a[0] * dn) | (f2bu(a[1] * dn) << 16);
            pk.y = f2bu(a[2] * dn) | (f2bu(a[3] * dn) << 16);
            pk.z = f2bu(a[4] * dn) | (f2bu(a[5] * dn) << 16);
            pk.w = f2bu(a[6] * dn) | (f2bu(a[7] * dn) << 16);
            *(uint4*)(OUT16 + ((size_t)n << 7) + hoff) = pk;
        }
        __syncthreads();  // protect sIdx/sdoff before next claim
    }
}

__device__ void gemm_tile(const unsigned short* __restrict__ A16,
                          const unsigned short* __restrict__ Wt,
                          unsigned short* __restrict__ outB, void* __restrict__ out,
                          const float* __restrict__ dinv, int mode, int isf,
                          const float* __restrict__ sF1, const float* __restrict__ sF2,
                          int t, int rowbase0) {
    int w = t >> 6, lane = t & 63, m16 = lane & 15, quad = lane >> 4;
    int rowbase = rowbase0 + w * 16;
    int rA = rowbase + m16;
    if (rA >= N_NODES) rA = N_NODES - 1;
    const size_t abase = (size_t)rA * 128 + (quad << 3);

    f32x4 acc[8];
#pragma unroll
    for (int ct = 0; ct < 8; ct++) acc[ct] = (f32x4){0.f, 0.f, 0.f, 0.f};
#pragma unroll
    for (int kk = 0; kk < 4; kk++) {
        bf16x8 af = *(const bf16x8*)(A16 + abase + kk * 32);
#pragma unroll
        for (int ct = 0; ct < 8; ct++) {
            bf16x8 bfr =
                *(const bf16x8*)(Wt + (size_t)((ct * 16 + m16) * 128) + kk * 32 + (quad << 3));
            acc[ct] = __builtin_amdgcn_mfma_f32_16x16x32_bf16(af, bfr, acc[ct], 0, 0, 0);
        }
    }

    int r0 = rowbase + quad * 4;
    if (mode) {
        float sc[8], of[8];
#pragma unroll
        for (int ct = 0; ct < 8; ct++) {
            sc[ct] = sF1[ct * 16 + m16];
            of[ct] = sF2[ct * 16 + m16];
        }
#pragma unroll
        for (int reg = 0; reg < 4; reg++) {
            int gr = r0 + reg;
            if (gr >= N_NODES) continue;
            float dn = dinv[gr];
            unsigned pk[4];
#pragma unroll
            for (int i = 0; i < 4; i++) {
                float v0 = fmaxf(acc[2 * i][reg] * sc[2 * i] + of[2 * i], 0.f) * dn;
                float v1 = fmaxf(acc[2 * i + 1][reg] * sc[2 * i + 1] + of[2 * i + 1], 0.f) * dn;
                pk[i] = f2bu(v0) | (f2bu(v1) << 16);
            }
            *(uint4*)(outB + (size_t)gr * 128 + (m16 << 3)) = make_uint4(pk[0], pk[1], pk[2], pk[3]);
        }
    } else {
        const size_t OFF_SIM = (size_t)N_NODES * OUT_C;
        const size_t OFF_HOM = OFF_SIM + (size_t)N_NODES * NUM_CLASSES;
        const size_t OFF_ENT = OFF_HOM + (size_t)N_NODES;
        float* outf = (float*)out;
        bf16* outb = (bf16*)out;
        float fb[8];
#pragma unroll
        for (int ct = 0; ct < 8; ct++) fb[ct] = sF1[ct * 16 + m16];
#define STORE_OUT(idx, v)                        \
    do {                                         \
        if (isf) outf[(idx)] = (v);              \
        else outb[(idx)] = __float2bfloat16(v);  \
    } while (0)
#pragma unroll
        for (int reg = 0; reg < 4; reg++) {
            int gr = r0 + reg;
            bool vrow = (gr < N_NODES);
            float v[8];
#pragma unroll
            for (int ct = 0; ct < 8; ct++) v[ct] = acc[ct][reg] + fb[ct];
            float m = fmaxf(fmaxf(v[0], v[1]), fmaxf(v[2], v[3]));
            m = fmaxf(m, __shfl_xor(m, 1));
            m = fmaxf(m, __shfl_xor(m, 2));
            m = fmaxf(m, __shfl_xor(m, 4));
            m = fmaxf(m, __shfl_xor(m, 8));
            float S = __expf(v[0] - m) + __expf(v[1] - m) + __expf(v[2] - m) + __expf(v[3] - m);
            S += __shfl_xor(S, 1);
            S += __shfl_xor(S, 2);
            S += __shfl_xor(S, 4);
            S += __shfl_xor(S, 8);
            float lS = m + __logf(S);
            if (vrow) {
#pragma unroll
                for (int ct = 0; ct < 4; ct++)
                    STORE_OUT((size_t)gr * OUT_C + ct * 16 + m16, v[ct] - lS);
            }
            bool has6 = (m16 < 8);
            float s4 = v[4], s5 = v[5], s6 = has6 ? v[6] : -INFINITY;
            float m2 = fmaxf(fmaxf(s4, s5), s6);
            m2 = fmaxf(m2, __shfl_xor(m2, 1));
            m2 = fmaxf(m2, __shfl_xor(m2, 2));
            m2 = fmaxf(m2, __shfl_xor(m2, 4));
            m2 = fmaxf(m2, __shfl_xor(m2, 8));
            float e4 = __expf(s4 - m2), e5 = __expf(s5 - m2), e6 = has6 ? __expf(s6 - m2) : 0.f;
            float S2 = e4 + e5 + e6;
            S2 += __shfl_xor(S2, 1);
            S2 += __shfl_xor(S2, 2);
            S2 += __shfl_xor(S2, 4);
            S2 += __shfl_xor(S2, 8);
            float rS2 = 1.f / S2;
            if (vrow) {
                STORE_OUT(OFF_SIM + (size_t)gr * NUM_CLASSES + m16, e4 * rS2);
                STORE_OUT(OFF_SIM + (size_t)gr * NUM_CLASSES + 16 + m16, e5 * rS2);
                if (has6) STORE_OUT(OFF_SIM + (size_t)gr * NUM_CLASSES + 32 + m16, e6 * rS2);
                if (m16 == 8) STORE_OUT(OFF_HOM + gr, 1.f / (1.f + __expf(-v[6])));
                if (m16 == 9) STORE_OUT(OFF_ENT + gr, 1.f / (1.f + __expf(-v[6])));
            }
        }
#undef STORE_OUT
    }
}

// ================= Cooperative mega-kernel (GB=256: 1 block/CU, guaranteed) =================
__global__ __launch_bounds__(BT, 4) void mega_kernel(
    const void* __restrict__ x, const int* __restrict__ ei, ParamSegs segs,
    float* __restrict__ params, unsigned short* __restrict__ wt, float* __restrict__ dinv,
    int* __restrict__ doffG, int* __restrict__ dcntG, int* __restrict__ bcur,
    int* __restrict__ wcnt, int* __restrict__ srcBuck, unsigned short* __restrict__ B16,
    unsigned short* __restrict__ G16, void* __restrict__ dout) {
    cg::grid_group grid = cg::this_grid();
#define GSYNC()          \
    do {                 \
        __threadfence(); \
        grid.sync();     \
        __threadfence(); \
    } while (0)

    __shared__ __align__(16) int sBig[2 * BCAP];  // 32 KB, reused per phase
    __shared__ int s128a[128], s128b[128], s128c[128];
    __shared__ float sF1[128], sF2[128];
    __shared__ int sCtl[2];

    const int t = threadIdx.x;
    const int bid = blockIdx.x;

    // phase 0: per-block dtype detect (wave 0 ballot)
    if (t < 64) {
        const unsigned* xw = (const unsigned*)x;
        unsigned wv = xw[t];
        unsigned e = (wv >> 23) & 0xFFu;
        unsigned long long m1 = __ballot(wv == 0u || (e >= 90u && e <= 160u));
        const unsigned* ew = (const unsigned*)ei;
        unsigned long long m2 = __ballot(ew[2 * t + 1] == 0u);
        if (t == 0) {
            sCtl[0] = (__popcll(m1) >= 48) ? 1 : 0;
            sCtl[1] = (__popcll(m2) >= 60) ? 1 : 0;
        }
    }
    __syncthreads();
    const int isf = sCtl[0], i64 = sCtl[1];
    __syncthreads();

    // phase 1: param convert + edge fill
    {
        int idx = bid * BT + t;
        if (idx < PRAW_TOTAL) {
            int k = 0;
#pragma unroll
            for (int s = 1; s < 16; s++)
                if (idx >= segs.dst[s]) k = s;
            int rel = idx - segs.dst[k];
            const void* sp = segs.src[k];
            params[idx] = isf ? ((const float*)sp)[rel] : __bfloat162float(((const bf16*)sp)[rel]);
        }
    }
    {
        int* hist = sBig;
        int* gbase = sBig + 1024;
        int* lcur = sBig + 2048;
        int e0 = bid * MEPB;
        int ecnt = N_EDGES - e0;
        if (ecnt > MEPB) ecnt = MEPB;
        for (int i = t; i < NBUCK; i += BT) hist[i] = 0;
        __syncthreads();
        int cc[MFITERS];
#pragma unroll
        for (int it = 0; it < MFITERS; ++it) {
            int i = t + it * BT;
            int c = -1;
            if (i < ecnt) {
                c = load_edge(ei, 1, e0 + i, i64);
                atomicAdd(&hist[c >> 7], 1);
            }
            cc[it] = c;
        }
        __syncthreads();
        for (int i = t; i < NBUCK; i += BT) {
            int c = hist[i];
            gbase[i] = (c > 0) ? atomicAdd(&bcur[i], c) : 0;
            lcur[i] = 0;
        }
        __syncthreads();
#pragma unroll
        for (int it = 0; it < MFITERS; ++it) {
            int i = t + it * BT;
            if (i < ecnt) {
                int c = cc[it];
                int r = load_edge(ei, 0, e0 + i, i64);
                int b = c >> 7;
                int p = gbase[b] + atomicAdd(&lcur[b], 1);
                if (p < BCAP) srcBuck[b * BCAP + p] = ((c & 127) << 17) | r;
            }
        }
    }
    GSYNC();

    // phase 2: fusew + per-bucket counting sort + dinv
    {
        int idx = bid * BT + t;
        if (idx < 16384) {
            int k = idx >> 7, c = idx & 127;
            float s = 0.f;
            for (int j = 0; j < 128; j++) s += params[PW2 + k * 128 + j] * headw(params, j, c);
            params[PFW + k * 128 + c] = s;
            if (k == 0) {
                float bs = 0.f;
                for (int j = 0; j < 128; j++) bs += params[PB2 + j] * headw(params, j, c);
                if (c < OUT_C) bs += params[PCLSB + c];
                else if (c < OUT_C + NUM_CLASSES) bs += params[PSIMB + c - OUT_C];
                else if (c == 104) bs += params[PHOMB];
                else if (c == 105) bs += params[PENTB];
                params[PFB + c] = bs;
            }
        }
    }
    for (int b = bid; b < NBUCK; b += GB) {
        int* raw = sBig;
        int* sorted = sBig + BCAP;
        int cnt = bcur[b];
        if (cnt > BCAP) cnt = BCAP;
        if (t < 128) s128a[t] = 0;
        __syncthreads();
        for (int i = t; i < cnt; i += BT) {
            int e = srcBuck[b * BCAP + i];
            raw[i] = e;
            atomicAdd(&s128a[e >> 17], 1);
        }
        __syncthreads();
        if (t < 128) s128b[t] = s128a[t];
        __syncthreads();
        for (int d = 1; d < 128; d <<= 1) {
            int add = 0;
            if (t < 128 && t >= d) add = s128b[t - d];
            __syncthreads();
            if (t < 128) s128b[t] += add;
            __syncthreads();
        }
        if (t < 128) {
            s128b[t] -= s128a[t];
            s128c[t] = 0;
        }
        __syncthreads();
        for (int i = t; i < cnt; i += BT) {
            int e = raw[i];
            int d = e >> 17;
            int r = atomicAdd(&s128c[d], 1);
            sorted[s128b[d] + r] = e & 0x1FFFF;
        }
        __syncthreads();
        for (int i = t; i < cnt; i += BT) srcBuck[b * BCAP + i] = sorted[i];
        if (t < 128) {
            doffG[(b << 7) + t] = s128b[t];
            dcntG[(b << 7) + t] = s128a[t];
            int n = (b << 7) + t;
            if (n < N_NODES) dinv[n] = rsqrtf((float)(s128a[t] + 1));
        }
        __syncthreads();
    }
    GSYNC();

    // phase 3: weight cvt + x cvt
    {
        int idx = bid * BT + t;
        if (idx < 32768) {
            int which = idx >> 14;
            int local = idx & 16383;
            int n = local >> 7, k = local & 127;
            int ksrc = which ? ((k & 7) * 16 + (k >> 3)) : k;
            float v = params[(which ? PFW : PW1) + ksrc * 128 + n];
            wt[(which << 14) + n * 128 + k] = (unsigned short)f2bu(v);
        }
    }
    for (int i4 = bid * BT + t; i4 < N_NODES * F / 4; i4 += GB * BT) {
        int n = i4 >> 5;
        float d = dinv[n];
        float v0, v1, v2, v3;
        if (isf) {
            float4 v = ((const float4*)x)[i4];
            v0 = v.x;
            v1 = v.y;
            v2 = v.z;
            v3 = v.w;
        } else {
            uint2 u = ((const uint2*)x)[i4];
            v0 = uasf(u.x << 16);
            v1 = uasf(u.x & 0xFFFF0000u);
            v2 = uasf(u.y << 16);
            v3 = uasf(u.y & 0xFFFF0000u);
        }
        uint2 o;
        o.x = f2bu(v0 * d) | (f2bu(v1 * d) << 16);
        o.y = f2bu(v2 * d) | (f2bu(v3 * d) << 16);
        ((uint2*)B16)[i4] = o;
    }
    GSYNC();

    // phase 4: layer-1 aggregation
    agg_phase(B16, G16, srcBuck, doffG, dcntG, dinv, wcnt, t, sBig, s128a, s128b, sCtl, BT);
    GSYNC();

    // phase 5: layer-1 GEMM + BN/ReLU epilogue
    if (t < 128) {
        float s = rsqrtf(params[PVAR + t] + BN_EPS) * params[PGAMMA + t];
        sF1[t] = s;
        sF2[t] = params[PB1 + t] * s + (params[PBETA + t] - params[PMEAN + t] * s);
    }
    __syncthreads();
    for (int tb = bid; tb < NBUCK; tb += GB)
        gemm_tile(G16, wt, B16, nullptr, dinv, 1, isf, sF1, sF2, t, tb << 7);
    GSYNC();

    // phase 6: layer-2 aggregation
    agg_phase(B16, G16, srcBuck, doffG, dcntG, dinv, wcnt + 2, t, sBig, s128a, s128b, sCtl, BT);
    GSYNC();

    // phase 7: layer-2 fused-head GEMM + softmax/sigmoid epilogue
    if (t < 128) sF1[t] = params[PFB + t];
    __syncthreads();
    for (int tb = bid; tb < NBUCK; tb += GB)
        gemm_tile(G16, wt + 16384, nullptr, dout, dinv, 0, isf, sF1, sF2, t, tb << 7);
#undef GSYNC
}

// ================= Fallback path: R6 proven multi-kernel pipeline =================
__global__ void detect_kernel(const void* __restrict__ x, const void* __restrict__ ei,
                              int* __restrict__ flags) {
    if (blockIdx.x != 0) return;
    int t = threadIdx.x & 63;
    const unsigned* xw = (const unsigned*)x;
    unsigned w = xw[t];
    unsigned e = (w >> 23) & 0xFFu;
    bool vote = (w == 0u || (e >= 90u && e <= 160u));
    unsigned long long m1 = __ballot(vote);
    const unsigned* ew = (const unsigned*)ei;
    bool zo = (ew[2 * t + 1] == 0u);
    unsigned long long m2 = __ballot(zo);
    if (t == 0) {
        flags[0] = (__popcll(m1) >= 48) ? 1 : 0;
        flags[1] = (__popcll(m2) >= 60) ? 1 : 0;
    }
}

__global__ void cvtparams_kernel(ParamSegs segs, float* __restrict__ params,
                                 const int* __restrict__ flags) {
    int idx = blockIdx.x * 256 + threadIdx.x;
    if (idx >= PRAW_TOTAL) return;
    int k = 0;
#pragma unroll
    for (int s = 1; s < 16; s++)
        if (idx >= segs.dst[s]) k = s;
    int rel = idx - segs.dst[k];
    const void* sp = segs.src[k];
    params[idx] = flags[0] ? ((const float*)sp)[rel] : __bfloat162float(((const bf16*)sp)[rel]);
}

__global__ __launch_bounds__(256) void fill2_kernel(const int* __restrict__ ei,
                                                    int* __restrict__ bcur,
                                                    int* __restrict__ srcBuck,
                                                    const int* __restrict__ flags) {
    __shared__ int hist[NBUCK];
    __shared__ int gbase[NBUCK];
    __shared__ int lcur[NBUCK];
    int blk = blockIdx.x;
    int t = threadIdx.x;
    int i64 = flags[1];
    int e0 = blk * EPB;
    int ecnt = N_EDGES - e0;
    if (ecnt > EPB) ecnt = EPB;
    for (int i = t; i < NBUCK; i += 256) hist[i] = 0;
    __syncthreads();
    int ccache[FILL_ITERS];
#pragma unroll
    for (int it = 0; it < FILL_ITERS; ++it) {
        int i = t + it * 256;
        int c = -1;
        if (i < ecnt) {
            c = load_edge(ei, 1, e0 + i, i64);
            atomicAdd(&hist[c >> 7], 1);
        }
        ccache[it] = c;
    }
    __syncthreads();
    for (int i = t; i < NBUCK; i += 256) {
        int c = hist[i];
        gbase[i] = (c > 0) ? atomicAdd(&bcur[i], c) : 0;
        lcur[i] = 0;
    }
    __syncthreads();
#pragma unroll
    for (int it = 0; it < FILL_ITERS; ++it) {
        int i = t + it * 256;
        if (i < ecnt) {
            int c = ccache[it];
            int r = load_edge(ei, 0, e0 + i, i64);
            int b = c >> 7;
            int p = gbase[b] + atomicAdd(&lcur[b], 1);
            if (p < BCAP) srcBuck[b * BCAP + p] = ((c & 127) << 17) | r;
        }
    }
}

__global__ __launch_bounds__(512) void presort_kernel(int* __restrict__ srcBuck,
                                                      const int* __restrict__ bcur,
                                                      int* __restrict__ doffG,
                                                      int* __restrict__ dcntG,
                                                      float* __restrict__ dinv) {
    __shared__ int raw[BCAP];
    __shared__ int sorted[BCAP];
    __shared__ int dcnt[128], doff[128], dcur[128];
    int b = blockIdx.x;
    int t = threadIdx.x;
    int cnt = bcur[b];
    if (cnt > BCAP) cnt = BCAP;
    if (t < 128) dcnt[t] = 0;
    __syncthreads();
    for (int i = t; i < cnt; i += 512) {
        int e = srcBuck[b * BCAP + i];
        raw[i] = e;
        atomicAdd(&dcnt[e >> 17], 1);
    }
    __syncthreads();
    if (t < 128) doff[t] = dcnt[t];
    __syncthreads();
    for (int d = 1; d < 128; d <<= 1) {
        int add = 0;
        if (t < 128 && t >= d) add = doff[t - d];
        __syncthreads();
        if (t < 128) doff[t] += add;
        __syncthreads();
    }
    if (t < 128) {
        doff[t] -= dcnt[t];
        dcur[t] = 0;
    }
    __syncthreads();
    for (int i = t; i < cnt; i += 512) {
        int e = raw[i];
        int d = e >> 17;
        int r = atomicAdd(&dcur[d], 1);
        sorted[doff[d] + r] = e & 0x1FFFF;
    }
    __syncthreads();
    for (int i = t; i < cnt; i += 512) srcBuck[b * BCAP + i] = sorted[i];
    if (t < 128) {
        doffG[(b << 7) + t] = doff[t];
        dcntG[(b << 7) + t] = dcnt[t];
        int n = (b << 7) + t;
        if (n < N_NODES) dinv[n] = rsqrtf((float)(dcnt[t] + 1));
    }
}

__global__ void cvtx_kernel(const void* __restrict__ x, const float* __restrict__ dinv,
                            unsigned short* __restrict__ B16, const int* __restrict__ flags) {
    int i4 = blockIdx.x * blockDim.x + threadIdx.x;
    if (i4 >= N_NODES * F / 4) return;
    int n = i4 >> 5;
    float d = dinv[n];
    float v0, v1, v2, v3;
    if (flags[0]) {
        float4 v = ((const float4*)x)[i4];
        v0 = v.x;
        v1 = v.y;
        v2 = v.z;
        v3 = v.w;
    } else {
        uint2 u = ((const uint2*)x)[i4];
        v0 = uasf(u.x << 16);
        v1 = uasf(u.x & 0xFFFF0000u);
        v2 = uasf(u.y << 16);
        v3 = uasf(u.y & 0xFFFF0000u);
    }
    uint2 o;
    o.x = f2bu(v0 * d) | (f2bu(v1 * d) << 16);
    o.y = f2bu(v2 * d) | (f2bu(v3 * d) << 16);
    ((uint2*)B16)[i4] = o;
}

__global__ void fusew_kernel(float* __restrict__ params) {
    int idx = blockIdx.x * 256 + threadIdx.x;
    int k = idx >> 7;
    int c = idx & 127;
    float s = 0.f;
    for (int j = 0; j < 128; j++) s += params[PW2 + k * 128 + j] * headw(params, j, c);
    params[PFW + k * 128 + c] = s;
    if (k == 0) {
        float b = 0.f;
        for (int j = 0; j < 128; j++) b += params[PB2 + j] * headw(params, j, c);
        if (c < OUT_C) b += params[PCLSB + c];
        else if (c < OUT_C + NUM_CLASSES) b += params[PSIMB + c - OUT_C];
        else if (c == 104) b += params[PHOMB];
        else if (c == 105) b += params[PENTB];
        params[PFB + c] = b;
    }
}

__global__ void wcvt_kernel(const float* __restrict__ params, unsigned short* __restrict__ wt) {
    int idx = blockIdx.x * 256 + threadIdx.x;  // 32768
    if (idx >= 32768) return;
    int which = idx >> 14;
    int local = idx & 16383;
    int n = local >> 7;
    int k = local & 127;
    int ksrc = which ? ((k & 7) * 16 + (k >> 3)) : k;
    float v = params[(which ? PFW : PW1) + ksrc * 128 + n];
    wt[(which << 14) + n * 128 + k] = (unsigned short)f2bu(v);
}

__global__ __launch_bounds__(512) void aggh_kernel(const unsigned short* __restrict__ IN16,
                                                   unsigned short* __restrict__ OUT16,
                                                   const int* __restrict__ srcBuck,
                                                   const int* __restrict__ doffG,
                                                   const int* __restrict__ dcntG,
                                                   const float* __restrict__ dinv,
                                                   int* __restrict__ wcnt) {
    __shared__ int sIdx[BCAP];
    __shared__ int sdoff[128], sdcnt[128];
    __shared__ int sCtl[2];
    int t = threadIdx.x;
    if (t == 0) {
        unsigned xcc;
        asm volatile("s_getreg_b32 %0, hwreg(HW_REG_XCC_ID)" : "=s"(xcc));
        int half = (xcc >> 2) & 1;
        int idx = atomicAdd(&wcnt[half], 1);
        if (idx >= NBUCK) {
            half ^= 1;
            idx = atomicAdd(&wcnt[half], 1);
        }
        sCtl[0] = idx;
        sCtl[1] = half;
    }
    __syncthreads();
    int b = sCtl[0], h = sCtl[1];
    if (b >= NBUCK) return;
    if (t < 128) {
        sdoff[t] = doffG[(b << 7) + t];
        sdcnt[t] = dcntG[(b << 7) + t];
    }
    __syncthreads();
    int cnt = sdoff[127] + sdcnt[127];
    for (int i = t; i < cnt; i += 512) sIdx[i] = srcBuck[b * BCAP + i];
    __syncthreads();

    int g8 = t >> 3;
    int hoff = h * 64 + ((t & 7) << 3);
    int base = b << 7;
    for (int d = g8; d < 128; d += 64) {
        int n = base + d;
        if (n >= N_NODES) break;
        float a[8] = {0.f, 0.f, 0.f, 0.f, 0.f, 0.f, 0.f, 0.f};
        {
            uint4 u = *(const uint4*)(IN16 + ((size_t)n << 7) + hoff);
            ACC8(u);
        }
        int o = sdoff[d], k = sdcnt[d];
        int j = 0;
        for (; j + 8 <= k; j += 8) {
            int s0 = sIdx[o + j + 0], s1 = sIdx[o + j + 1];
            int s2 = sIdx[o + j + 2], s3 = sIdx[o + j + 3];
            int s4 = sIdx[o + j + 4], s5 = sIdx[o + j + 5];
            int s6 = sIdx[o + j + 6], s7 = sIdx[o + j + 7];
            uint4 u0 = *(const uint4*)(IN16 + ((size_t)s0 << 7) + hoff);
            uint4 u1 = *(const uint4*)(IN16 + ((size_t)s1 << 7) + hoff);
            uint4 u2 = *(const uint4*)(IN16 + ((size_t)s2 << 7) + hoff);
            uint4 u3 = *(const uint4*)(IN16 + ((size_t)s3 << 7) + hoff);
            uint4 u4 = *(const uint4*)(IN16 + ((size_t)s4 << 7) + hoff);
            uint4 u5 = *(const uint4*)(IN16 + ((size_t)s5 << 7) + hoff);
            uint4 u6 = *(const uint4*)(IN16 + ((size_t)s6 << 7) + hoff);
            uint4 u7 = *(const uint4*)(IN16 + ((size_t)s7 << 7) + hoff);
            ACC8(u0);
            ACC8(u1);
            ACC8(u2);
            ACC8(u3);
            ACC8(u4);
            ACC8(u5);
            ACC8(u6);
            ACC8(u7);
        }
        for (; j + 4 <= k; j += 4) {
            int s0 = sIdx[o + j + 0], s1 = sIdx[o + j + 1];
            int s2 = sIdx[o + j + 2], s3 = sIdx[o + j + 3];
            uint4 u0 = *(const uint4*)(IN16 + ((size_t)s0 << 7) + hoff);
            uint4 u1 = *(const uint4*)(IN16 + ((size_t)s1 << 7) + hoff);
            uint4 u2 = *(const uint4*)(IN16 + ((size_t)s2 << 7) + hoff);
            uint4 u3 = *(const uint4*)(IN16 + ((size_t)s3 << 7) + hoff);
            ACC8(u0);
            ACC8(u1);
            ACC8(u2);
            ACC8(u3);
        }
        for (; j < k; j++) {
            int s0 = sIdx[o + j];
            uint4 u0 = *(const uint4*)(IN16 + ((size_t)s0 << 7) + hoff);
            ACC8(u0);
        }
        float dn = dinv[n];
        uint4 pk;
        pk.x = f2bu(a[0] * dn) | (f2bu(a[1] * dn) << 16);
        pk.y = f2bu(a[2] * dn) | (f2bu(a[3] * dn) << 16);
        pk.z = f2bu(a[4] * dn) | (f2bu(a[5] * dn) << 16);
        pk.w = f2bu(a[6] * dn) | (f2bu(a[7] * dn) << 16);
        *(uint4*)(OUT16 + ((size_t)n << 7) + hoff) = pk;
    }
}

__global__ __launch_bounds__(256) void gemm_mfma_kernel(
    const unsigned short* __restrict__ A16, const unsigned short* __restrict__ Wt,
    unsigned short* __restrict__ outB, void* __restrict__ out,
    const float* __restrict__ params, const float* __restrict__ dinv, int mode,
    const int* __restrict__ flags) {
    __shared__ float sF1[128], sF2[128];
    int t = threadIdx.x;
    if (t < 128) {
        if (mode) {
            float s = rsqrtf(params[PVAR + t] + BN_EPS) * params[PGAMMA + t];
            sF1[t] = s;
            sF2[t] = params[PB1 + t] * s + (params[PBETA + t] - params[PMEAN + t] * s);
        } else {
            sF1[t] = params[PFB + t];
        }
    }
    __syncthreads();
    gemm_tile(A16, Wt, outB, out, dinv, mode, flags[0], sF1, sF2, t, blockIdx.x * 64 - ((t >> 6) * 16) + ((t >> 6) * 16));
}

// ---------------- Launch ----------------
extern "C" void kernel_launch(void* const* d_in, const int* in_sizes, int n_in,
                              void* d_out, int out_size, void* d_ws, size_t ws_size,
                              hipStream_t stream) {
    const void* x = d_in[0];
    const int* ei = (const int*)d_in[1];

    char* ws = (char*)d_ws;
    size_t o = 0;
    auto alloc = [&](size_t bytes) {
        size_t r = o;
        o = (o + bytes + 255) & ~(size_t)255;
        return r;
    };
    char* RA = ws + alloc((size_t)51 * 1024 * 1024);  // srcBuck + B16
    char* RB = ws + alloc((size_t)26 * 1024 * 1024);  // G16
    float* params = (float*)(ws + alloc((size_t)PTOTAL * 4));
    unsigned short* wt = (unsigned short*)(ws + alloc(65536));
    float* dinv = (float*)(ws + alloc((size_t)N_NODES * 4));
    int* doffG = (int*)(ws + alloc((size_t)NBUCK * 128 * 4));
    int* dcntG = (int*)(ws + alloc((size_t)NBUCK * 128 * 4));
    int* bcur = (int*)(ws + alloc((size_t)(NBUCK + 8) * 4));
    int* wcnt = (int*)(ws + alloc(256));
    int* flags = (int*)(ws + alloc(256));

    int* srcBuck = (int*)RA;
    unsigned short* B16 = (unsigned short*)(RA + 13u * 1024 * 1024);
    unsigned short* G16 = (unsigned short*)RB;

    hipMemsetAsync(bcur, 0, (size_t)((char*)wcnt + 256 - (char*)bcur), stream);

    ParamSegs segs;
    const int srcIdx[16] = {2, 3, 4, 5, 6, 7, 8, 9, 10, 11, 12, 13, 14, 15, 16, 17};
    const int dsts[16] = {PW1, PB1, PW2, PB2, PGAMMA, PBETA, PMEAN, PVAR,
                          PCLSW, PCLSB, PSIMW, PSIMB, PHOMW, PHOMB, PENTW, PENTB};
    for (int k = 0; k < 16; k++) {
        segs.src[k] = d_in[srcIdx[k]];
        segs.dst[k] = dsts[k];
    }

    void* kargs[] = {(void*)&x,    (void*)&ei,   (void*)&segs,    (void*)&params,
                     (void*)&wt,   (void*)&dinv, (void*)&doffG,   (void*)&dcntG,
                     (void*)&bcur, (void*)&wcnt, (void*)&srcBuck, (void*)&B16,
                     (void*)&G16,  (void*)&d_out};
    hipError_t cerr =
        hipLaunchCooperativeKernel((void*)mega_kernel, dim3(GB), dim3(BT), kargs, 0, stream);

    if (cerr != hipSuccess) {
        // ---- fallback: R6 proven multi-kernel pipeline ----
        detect_kernel<<<1, 64, 0, stream>>>(x, ei, flags);
        cvtparams_kernel<<<(PRAW_TOTAL + 255) / 256, 256, 0, stream>>>(segs, params, flags);
        fusew_kernel<<<64, 256, 0, stream>>>(params);
        wcvt_kernel<<<128, 256, 0, stream>>>(params, wt);
        fill2_kernel<<<FILL_BLOCKS, 256, 0, stream>>>(ei, bcur, srcBuck, flags);
        presort_kernel<<<NBUCK, 512, 0, stream>>>(srcBuck, bcur, doffG, dcntG, dinv);
        cvtx_kernel<<<(N_NODES * F / 4 + 255) / 256, 256, 0, stream>>>(x, dinv, B16, flags);
        const int gemmGrid = (N_NODES + 63) / 64;
        aggh_kernel<<<2 * NBUCK, 512, 0, stream>>>(B16, G16, srcBuck, doffG, dcntG, dinv, wcnt);
        gemm_mfma_kernel<<<gemmGrid, 256, 0, stream>>>(G16, wt, B16, nullptr, params, dinv, 1,
                                                       flags);
        aggh_kernel<<<2 * NBUCK, 512, 0, stream>>>(B16, G16, srcBuck, doffG, dcntG, dinv,
                                                   wcnt + 2);
        gemm_mfma_kernel<<<gemmGrid, 256, 0, stream>>>(G16, wt + 16384, nullptr, d_out, params,
                                                       dinv, 0, flags);
    }
}

// Round 9
// 438.627 us; speedup vs baseline: 2.6575x; 2.6575x over previous
//
#include <hip/hip_runtime.h>
#include <hip/hip_bf16.h>
#include <math.h>

#define N_NODES 100000
#define N_EDGES 1600000
#define F 128
#define OUT_C 64
#define NUM_CLASSES 40
#define BN_EPS 1e-5f

#define NBUCK 782   // ceil(100000/128) buckets of 128 destination nodes
#define BCAP 4096   // per-bucket edge capacity
#define FILL_BLOCKS 512
#define EPB ((N_EDGES + FILL_BLOCKS - 1) / FILL_BLOCKS)  // 3125
#define FILL_ITERS 13  // ceil(EPB/256)

// tiny folded-constant block (replaces the old 64KB params buffer)
#define PSC 0     // [0..127]   BN scale s = rsqrt(var+eps)*gamma
#define POF 128   // [128..255] BN offset o = b1*s + beta - mean*s
#define PFB2 256  // [256..383] fused head bias

typedef __hip_bfloat16 bf16;
typedef __attribute__((ext_vector_type(8))) short bf16x8;
typedef __attribute__((ext_vector_type(4))) float f32x4;

struct ParamSegs {
    const void* src[16];  // [0]=w1 [1]=b1 [2]=w2 [3]=b2 [4]=gamma [5]=beta [6]=mean [7]=var
                          // [8]=cls_w [9]=cls_b [10]=sim_w [11]=sim_b [12]=hom_w [13]=hom_b
                          // [14]=ent_w [15]=ent_b
    int dst[16];          // unused (kept for ABI stability)
};

__device__ __forceinline__ float uasf(unsigned u) { return __uint_as_float(u); }
__device__ __forceinline__ unsigned f2bu(float f) {
    bf16 h = __float2bfloat16(f);
    return (unsigned)*(unsigned short*)&h;
}
__device__ __forceinline__ float ldp(const void* p, int i, int isf) {
    return isf ? ((const float*)p)[i] : __bfloat162float(((const bf16*)p)[i]);
}
__device__ __forceinline__ int load_edge(const int* __restrict__ ei, int which, int i, int i64) {
    size_t elem = (size_t)which * N_EDGES + (size_t)i;
    return i64 ? ei[elem * 2] : ei[elem];
}
// per-block dtype detect: wave-0 ballot over the same 64 words (L2-broadcast, ~free)
__device__ __forceinline__ int detect_isf(const void* x, int t, int* sflag) {
    if (t < 64) {
        unsigned w = ((const unsigned*)x)[t];
        unsigned e = (w >> 23) & 0xFFu;
        unsigned long long m = __ballot(w == 0u || (e >= 90u && e <= 160u));
        if (t == 0) *sflag = (__popcll(m) >= 48) ? 1 : 0;
    }
    __syncthreads();
    return *sflag;
}
__device__ __forceinline__ int detect_i64(const void* ei, int t, int* sflag) {
    if (t < 64) {
        unsigned long long m = __ballot(((const unsigned*)ei)[2 * t + 1] == 0u);
        if (t == 0) *sflag = (__popcll(m) >= 60) ? 1 : 0;
    }
    __syncthreads();
    return *sflag;
}
__device__ __forceinline__ float headw_raw(const ParamSegs& segs, int j, int c, int isf) {
    if (c < OUT_C) return ldp(segs.src[8], j * OUT_C + c, isf);
    if (c < OUT_C + NUM_CLASSES) return ldp(segs.src[10], j * NUM_CLASSES + (c - OUT_C), isf);
    if (c == 104) return ldp(segs.src[12], j, isf);
    if (c == 105) return ldp(segs.src[14], j, isf);
    return 0.f;
}

#define ACC8(u)                                \
    do {                                       \
        a[0] += uasf((u).x << 16);             \
        a[1] += uasf((u).x & 0xFFFF0000u);     \
        a[2] += uasf((u).y << 16);             \
        a[3] += uasf((u).y & 0xFFFF0000u);     \
        a[4] += uasf((u).z << 16);             \
        a[5] += uasf((u).z & 0xFFFF0000u);     \
        a[6] += uasf((u).w << 16);             \
        a[7] += uasf((u).w & 0xFFFF0000u);     \
    } while (0)

// ---------------- fill: block-local LDS hist -> one reservation per (block,bucket) ----------
__global__ __launch_bounds__(256) void fill2_kernel(const int* __restrict__ ei,
                                                    int* __restrict__ bcur,
                                                    int* __restrict__ srcBuck) {
    __shared__ int hist[NBUCK];
    __shared__ int gbase[NBUCK];
    __shared__ int lcur[NBUCK];
    __shared__ int sflag;
    int blk = blockIdx.x;
    int t = threadIdx.x;
    int i64 = detect_i64(ei, t, &sflag);
    int e0 = blk * EPB;
    int ecnt = N_EDGES - e0;
    if (ecnt > EPB) ecnt = EPB;
    for (int i = t; i < NBUCK; i += 256) hist[i] = 0;
    __syncthreads();
    int ccache[FILL_ITERS];
#pragma unroll
    for (int it = 0; it < FILL_ITERS; ++it) {
        int i = t + it * 256;
        int c = -1;
        if (i < ecnt) {
            c = load_edge(ei, 1, e0 + i, i64);
            atomicAdd(&hist[c >> 7], 1);
        }
        ccache[it] = c;
    }
    __syncthreads();
    for (int i = t; i < NBUCK; i += 256) {
        int c = hist[i];
        gbase[i] = (c > 0) ? atomicAdd(&bcur[i], c) : 0;
        lcur[i] = 0;
    }
    __syncthreads();
#pragma unroll
    for (int it = 0; it < FILL_ITERS; ++it) {
        int i = t + it * 256;
        if (i < ecnt) {
            int c = ccache[it];
            int r = load_edge(ei, 0, e0 + i, i64);
            int b = c >> 7;
            int p = gbase[b] + atomicAdd(&lcur[b], 1);
            if (p < BCAP) srcBuck[b * BCAP + p] = ((c & 127) << 17) | r;
        }
    }
}

// ---------------- presort: one-time LDS counting sort per bucket, in-place ----------------
__global__ __launch_bounds__(512) void presort_kernel(int* __restrict__ srcBuck,
                                                      const int* __restrict__ bcur,
                                                      int* __restrict__ doffG,
                                                      int* __restrict__ dcntG,
                                                      float* __restrict__ dinv) {
    __shared__ int raw[BCAP];
    __shared__ int sorted[BCAP];
    __shared__ int dcnt[128], doff[128], dcur[128];
    int b = blockIdx.x;
    int t = threadIdx.x;
    int cnt = bcur[b];
    if (cnt > BCAP) cnt = BCAP;
    if (t < 128) dcnt[t] = 0;
    __syncthreads();
    for (int i = t; i < cnt; i += 512) {
        int e = srcBuck[b * BCAP + i];
        raw[i] = e;
        atomicAdd(&dcnt[e >> 17], 1);
    }
    __syncthreads();
    if (t < 128) doff[t] = dcnt[t];
    __syncthreads();
    for (int d = 1; d < 128; d <<= 1) {
        int add = 0;
        if (t < 128 && t >= d) add = doff[t - d];
        __syncthreads();
        if (t < 128) doff[t] += add;
        __syncthreads();
    }
    if (t < 128) {
        doff[t] -= dcnt[t];
        dcur[t] = 0;
    }
    __syncthreads();
    for (int i = t; i < cnt; i += 512) {
        int e = raw[i];
        int d = e >> 17;
        int r = atomicAdd(&dcur[d], 1);
        sorted[doff[d] + r] = e & 0x1FFFF;
    }
    __syncthreads();
    for (int i = t; i < cnt; i += 512) srcBuck[b * BCAP + i] = sorted[i];
    if (t < 128) {
        doffG[(b << 7) + t] = doff[t];
        dcntG[(b << 7) + t] = dcnt[t];
        int n = (b << 7) + t;
        if (n < N_NODES) dinv[n] = rsqrtf((float)(dcnt[t] + 1));
    }
}

// ---------------- cvtx + weight-prep + const-fold, ONE kernel ----------------
// Replaces detect/cvtparams/fusew/wcvt/cvtx (4 dispatches + 64KB params round-trips).
// bid < 12500            : x -> bf16 prescaled by dinv (exact cover of 3.2M uint2 items)
// bid in [12500,12628)   : wt2 = bf16(Wfuse^T permuted), wt1 = bf16(W1^T), from RAW inputs
// bid == 12628           : BN scale/offset + fused head bias -> params[0..383]
#define CVTX_BLOCKS 12500
__global__ __launch_bounds__(256) void cvtxprep_kernel(const void* __restrict__ x,
                                                       ParamSegs segs,
                                                       const float* __restrict__ dinv,
                                                       unsigned short* __restrict__ B16,
                                                       float* __restrict__ params,
                                                       unsigned short* __restrict__ wt) {
    __shared__ int sflag;
    int t = threadIdx.x;
    int bid = blockIdx.x;
    int isf = detect_isf(x, t, &sflag);

    if (bid < CVTX_BLOCKS) {
        int i4 = bid * 256 + t;  // exactly N_NODES*F/4 items
        int n = i4 >> 5;
        float d = dinv[n];
        float v0, v1, v2, v3;
        if (isf) {
            float4 v = ((const float4*)x)[i4];
            v0 = v.x; v1 = v.y; v2 = v.z; v3 = v.w;
        } else {
            uint2 u = ((const uint2*)x)[i4];
            v0 = uasf(u.x << 16);
            v1 = uasf(u.x & 0xFFFF0000u);
            v2 = uasf(u.y << 16);
            v3 = uasf(u.y & 0xFFFF0000u);
        }
        uint2 o;
        o.x = f2bu(v0 * d) | (f2bu(v1 * d) << 16);
        o.y = f2bu(v2 * d) | (f2bu(v3 * d) << 16);
        ((uint2*)B16)[i4] = o;
    } else if (bid < CVTX_BLOCKS + 128) {
        int idx = (bid - CVTX_BLOCKS) * 256 + t;  // 32768
        if (idx < 16384) {
            // Wfuse[kf][c] = sum_j W2[kf][j] * headw[j][c]; store at wt2[c*128 + p],
            // p = (kf&15)*8 + (kf>>4)  (inverse of colOf(p) = (p&7)*16 + (p>>3))
            int kf = idx >> 7, c = idx & 127;
            const void* w2 = segs.src[2];
            float s = 0.f;
            for (int j = 0; j < 128; j++) s += ldp(w2, kf * 128 + j, isf) * headw_raw(segs, j, c, isf);
            int p = (kf & 15) * 8 + (kf >> 4);
            wt[16384 + c * 128 + p] = (unsigned short)f2bu(s);
        } else {
            // wt1[n*128+k] = W1[k][n]
            int l = idx - 16384;
            int n = l >> 7, k = l & 127;
            wt[n * 128 + k] = (unsigned short)f2bu(ldp(segs.src[0], k * 128 + n, isf));
        }
    } else {
        if (t < 128) {
            float s = rsqrtf(ldp(segs.src[7], t, isf) + BN_EPS) * ldp(segs.src[4], t, isf);
            params[PSC + t] = s;
            params[POF + t] =
                ldp(segs.src[1], t, isf) * s + ldp(segs.src[5], t, isf) - ldp(segs.src[6], t, isf) * s;
            float b = 0.f;
            for (int j = 0; j < 128; j++) b += ldp(segs.src[3], j, isf) * headw_raw(segs, j, t, isf);
            if (t < OUT_C) b += ldp(segs.src[9], t, isf);
            else if (t < OUT_C + NUM_CLASSES) b += ldp(segs.src[11], t - OUT_C, isf);
            else if (t == 104) b += ldp(segs.src[13], 0, isf);
            else if (t == 105) b += ldp(segs.src[15], 0, isf);
            params[PFB2 + t] = b;
        }
    }
}

// ---------------- Half-feature aggregation (R6-proven: 65us, FETCH 159MB) ----------------
__global__ __launch_bounds__(512) void aggh_kernel(const unsigned short* __restrict__ IN16,
                                                   unsigned short* __restrict__ OUT16,
                                                   const int* __restrict__ srcBuck,
                                                   const int* __restrict__ doffG,
                                                   const int* __restrict__ dcntG,
                                                   const float* __restrict__ dinv,
                                                   int* __restrict__ wcnt) {
    __shared__ int sIdx[BCAP];
    __shared__ int sdoff[128], sdcnt[128];
    __shared__ int sCtl[2];
    int t = threadIdx.x;
    if (t == 0) {
        unsigned xcc;
        asm volatile("s_getreg_b32 %0, hwreg(HW_REG_XCC_ID)" : "=s"(xcc));
        int half = (xcc >> 2) & 1;
        int idx = atomicAdd(&wcnt[half], 1);
        if (idx >= NBUCK) {
            half ^= 1;
            idx = atomicAdd(&wcnt[half], 1);
        }
        sCtl[0] = idx;
        sCtl[1] = half;
    }
    __syncthreads();
    int b = sCtl[0], h = sCtl[1];
    if (b >= NBUCK) return;
    if (t < 128) {
        sdoff[t] = doffG[(b << 7) + t];
        sdcnt[t] = dcntG[(b << 7) + t];
    }
    __syncthreads();
    int cnt = sdoff[127] + sdcnt[127];
    for (int i = t; i < cnt; i += 512) sIdx[i] = srcBuck[b * BCAP + i];
    __syncthreads();

    int g8 = t >> 3;
    int hoff = h * 64 + ((t & 7) << 3);
    int base = b << 7;
    for (int d = g8; d < 128; d += 64) {
        int n = base + d;
        if (n >= N_NODES) break;
        float a[8] = {0.f, 0.f, 0.f, 0.f, 0.f, 0.f, 0.f, 0.f};
        {
            uint4 u = *(const uint4*)(IN16 + ((size_t)n << 7) + hoff);
            ACC8(u);
        }
        int o = sdoff[d], k = sdcnt[d];
        int j = 0;
        for (; j + 8 <= k; j += 8) {
            int s0 = sIdx[o + j + 0], s1 = sIdx[o + j + 1];
            int s2 = sIdx[o + j + 2], s3 = sIdx[o + j + 3];
            int s4 = sIdx[o + j + 4], s5 = sIdx[o + j + 5];
            int s6 = sIdx[o + j + 6], s7 = sIdx[o + j + 7];
            uint4 u0 = *(const uint4*)(IN16 + ((size_t)s0 << 7) + hoff);
            uint4 u1 = *(const uint4*)(IN16 + ((size_t)s1 << 7) + hoff);
            uint4 u2 = *(const uint4*)(IN16 + ((size_t)s2 << 7) + hoff);
            uint4 u3 = *(const uint4*)(IN16 + ((size_t)s3 << 7) + hoff);
            uint4 u4 = *(const uint4*)(IN16 + ((size_t)s4 << 7) + hoff);
            uint4 u5 = *(const uint4*)(IN16 + ((size_t)s5 << 7) + hoff);
            uint4 u6 = *(const uint4*)(IN16 + ((size_t)s6 << 7) + hoff);
            uint4 u7 = *(const uint4*)(IN16 + ((size_t)s7 << 7) + hoff);
            ACC8(u0);
            ACC8(u1);
            ACC8(u2);
            ACC8(u3);
            ACC8(u4);
            ACC8(u5);
            ACC8(u6);
            ACC8(u7);
        }
        for (; j + 4 <= k; j += 4) {
            int s0 = sIdx[o + j + 0], s1 = sIdx[o + j + 1];
            int s2 = sIdx[o + j + 2], s3 = sIdx[o + j + 3];
            uint4 u0 = *(const uint4*)(IN16 + ((size_t)s0 << 7) + hoff);
            uint4 u1 = *(const uint4*)(IN16 + ((size_t)s1 << 7) + hoff);
            uint4 u2 = *(const uint4*)(IN16 + ((size_t)s2 << 7) + hoff);
            uint4 u3 = *(const uint4*)(IN16 + ((size_t)s3 << 7) + hoff);
            ACC8(u0);
            ACC8(u1);
            ACC8(u2);
            ACC8(u3);
        }
        for (; j < k; j++) {
            int s0 = sIdx[o + j];
            uint4 u0 = *(const uint4*)(IN16 + ((size_t)s0 << 7) + hoff);
            ACC8(u0);
        }
        float dn = dinv[n];
        uint4 pk;
        pk.x = f2bu(a[0] * dn) | (f2bu(a[1] * dn) << 16);
        pk.y = f2bu(a[2] * dn) | (f2bu(a[3] * dn) << 16);
        pk.z = f2bu(a[4] * dn) | (f2bu(a[5] * dn) << 16);
        pk.w = f2bu(a[6] * dn) | (f2bu(a[7] * dn) << 16);
        *(uint4*)(OUT16 + ((size_t)n << 7) + hoff) = pk;
    }
}

// ---------------- MFMA GEMM (R6-proven math; consts from tiny params block) --------------
__global__ __launch_bounds__(256) void gemm_mfma_kernel(
    const unsigned short* __restrict__ A16, const unsigned short* __restrict__ Wt,
    unsigned short* __restrict__ outB, void* __restrict__ out,
    const float* __restrict__ params, const float* __restrict__ dinv, int mode,
    const void* __restrict__ x) {
    __shared__ float sF1[128], sF2[128];
    __shared__ int sflag;
    int t = threadIdx.x;
    int isf = detect_isf(x, t, &sflag);
    if (t < 128) {
        if (mode) {
            sF1[t] = params[PSC + t];
            sF2[t] = params[POF + t];
        } else {
            sF1[t] = params[PFB2 + t];
        }
    }
    __syncthreads();
    int wave = t >> 6, lane = t & 63, m16 = lane & 15, quad = lane >> 4;
    int rowbase = blockIdx.x * 64 + wave * 16;
    int rA = rowbase + m16;
    if (rA >= N_NODES) rA = N_NODES - 1;
    const size_t abase = (size_t)rA * 128 + (quad << 3);

    f32x4 acc[8];
#pragma unroll
    for (int ct = 0; ct < 8; ct++) acc[ct] = (f32x4){0.f, 0.f, 0.f, 0.f};
#pragma unroll
    for (int kk = 0; kk < 4; kk++) {
        bf16x8 af = *(const bf16x8*)(A16 + abase + kk * 32);
#pragma unroll
        for (int ct = 0; ct < 8; ct++) {
            bf16x8 bfr = *(const bf16x8*)(Wt + (size_t)((ct * 16 + m16) * 128) + kk * 32 + (quad << 3));
            acc[ct] = __builtin_amdgcn_mfma_f32_16x16x32_bf16(af, bfr, acc[ct], 0, 0, 0);
        }
    }

    int r0 = rowbase + quad * 4;
    if (mode) {
        float sc[8], of[8];
#pragma unroll
        for (int ct = 0; ct < 8; ct++) {
            sc[ct] = sF1[ct * 16 + m16];
            of[ct] = sF2[ct * 16 + m16];
        }
#pragma unroll
        for (int reg = 0; reg < 4; reg++) {
            int gr = r0 + reg;
            if (gr >= N_NODES) continue;
            float dn = dinv[gr];
            unsigned pk[4];
#pragma unroll
            for (int i = 0; i < 4; i++) {
                float v0 = fmaxf(acc[2 * i][reg] * sc[2 * i] + of[2 * i], 0.f) * dn;
                float v1 = fmaxf(acc[2 * i + 1][reg] * sc[2 * i + 1] + of[2 * i + 1], 0.f) * dn;
                pk[i] = f2bu(v0) | (f2bu(v1) << 16);
            }
            *(uint4*)(outB + (size_t)gr * 128 + (m16 << 3)) = make_uint4(pk[0], pk[1], pk[2], pk[3]);
        }
    } else {
        const size_t OFF_SIM = (size_t)N_NODES * OUT_C;
        const size_t OFF_HOM = OFF_SIM + (size_t)N_NODES * NUM_CLASSES;
        const size_t OFF_ENT = OFF_HOM + (size_t)N_NODES;
        float* outf = (float*)out;
        bf16* outb = (bf16*)out;
        float fb[8];
#pragma unroll
        for (int ct = 0; ct < 8; ct++) fb[ct] = sF1[ct * 16 + m16];
#define STORE_OUT(idx, v)                        \
    do {                                         \
        if (isf) outf[(idx)] = (v);              \
        else outb[(idx)] = __float2bfloat16(v);  \
    } while (0)
#pragma unroll
        for (int reg = 0; reg < 4; reg++) {
            int gr = r0 + reg;
            bool vrow = (gr < N_NODES);
            float v[8];
#pragma unroll
            for (int ct = 0; ct < 8; ct++) v[ct] = acc[ct][reg] + fb[ct];
            float m = fmaxf(fmaxf(v[0], v[1]), fmaxf(v[2], v[3]));
            m = fmaxf(m, __shfl_xor(m, 1));
            m = fmaxf(m, __shfl_xor(m, 2));
            m = fmaxf(m, __shfl_xor(m, 4));
            m = fmaxf(m, __shfl_xor(m, 8));
            float S = __expf(v[0] - m) + __expf(v[1] - m) + __expf(v[2] - m) + __expf(v[3] - m);
            S += __shfl_xor(S, 1);
            S += __shfl_xor(S, 2);
            S += __shfl_xor(S, 4);
            S += __shfl_xor(S, 8);
            float lS = m + __logf(S);
            if (vrow) {
#pragma unroll
                for (int ct = 0; ct < 4; ct++)
                    STORE_OUT((size_t)gr * OUT_C + ct * 16 + m16, v[ct] - lS);
            }
            bool has6 = (m16 < 8);
            float s4 = v[4], s5 = v[5], s6 = has6 ? v[6] : -INFINITY;
            float m2 = fmaxf(fmaxf(s4, s5), s6);
            m2 = fmaxf(m2, __shfl_xor(m2, 1));
            m2 = fmaxf(m2, __shfl_xor(m2, 2));
            m2 = fmaxf(m2, __shfl_xor(m2, 4));
            m2 = fmaxf(m2, __shfl_xor(m2, 8));
            float e4 = __expf(s4 - m2), e5 = __expf(s5 - m2), e6 = has6 ? __expf(s6 - m2) : 0.f;
            float S2 = e4 + e5 + e6;
            S2 += __shfl_xor(S2, 1);
            S2 += __shfl_xor(S2, 2);
            S2 += __shfl_xor(S2, 4);
            S2 += __shfl_xor(S2, 8);
            float rS2 = 1.f / S2;
            if (vrow) {
                STORE_OUT(OFF_SIM + (size_t)gr * NUM_CLASSES + m16, e4 * rS2);
                STORE_OUT(OFF_SIM + (size_t)gr * NUM_CLASSES + 16 + m16, e5 * rS2);
                if (has6) STORE_OUT(OFF_SIM + (size_t)gr * NUM_CLASSES + 32 + m16, e6 * rS2);
                if (m16 == 8) STORE_OUT(OFF_HOM + gr, 1.f / (1.f + __expf(-v[6])));
                if (m16 == 9) STORE_OUT(OFF_ENT + gr, 1.f / (1.f + __expf(-v[6])));
            }
        }
#undef STORE_OUT
    }
}

// ---------------- Launch: 8 queue items (was 12) ----------------
extern "C" void kernel_launch(void* const* d_in, const int* in_sizes, int n_in,
                              void* d_out, int out_size, void* d_ws, size_t ws_size,
                              hipStream_t stream) {
    const void* x = d_in[0];
    const int* ei = (const int*)d_in[1];

    char* ws = (char*)d_ws;
    size_t o = 0;
    auto alloc = [&](size_t bytes) {
        size_t r = o;
        o = (o + bytes + 255) & ~(size_t)255;
        return r;
    };
    char* RA = ws + alloc((size_t)51 * 1024 * 1024);  // srcBuck + B16
    char* RB = ws + alloc((size_t)26 * 1024 * 1024);  // G16
    float* params = (float*)(ws + alloc(2048));
    unsigned short* wt = (unsigned short*)(ws + alloc(65536));
    float* dinv = (float*)(ws + alloc((size_t)N_NODES * 4));
    int* doffG = (int*)(ws + alloc((size_t)NBUCK * 128 * 4));
    int* dcntG = (int*)(ws + alloc((size_t)NBUCK * 128 * 4));
    int* bcur = (int*)(ws + alloc((size_t)(NBUCK + 8) * 4));
    int* wcnt = (int*)(ws + alloc(256));  // 4 counters: layer1 pair, layer2 pair

    int* srcBuck = (int*)RA;                                          // 12.81 MB
    unsigned short* B16 = (unsigned short*)(RA + 13u * 1024 * 1024);  // 25.6 MB
    unsigned short* G16 = (unsigned short*)RB;                        // 25.6 MB

    // one memset spans bcur..wcnt (adjacent allocs)
    hipMemsetAsync(bcur, 0, (size_t)((char*)wcnt + 256 - (char*)bcur), stream);

    ParamSegs segs;
    const int srcIdx[16] = {2, 3, 4, 5, 6, 7, 8, 9, 10, 11, 12, 13, 14, 15, 16, 17};
    for (int k = 0; k < 16; k++) {
        segs.src[k] = d_in[srcIdx[k]];
        segs.dst[k] = 0;
    }

    fill2_kernel<<<FILL_BLOCKS, 256, 0, stream>>>(ei, bcur, srcBuck);
    presort_kernel<<<NBUCK, 512, 0, stream>>>(srcBuck, bcur, doffG, dcntG, dinv);
    cvtxprep_kernel<<<CVTX_BLOCKS + 129, 256, 0, stream>>>(x, segs, dinv, B16, params, wt);

    const int gemmGrid = (N_NODES + 63) / 64;
    // layer 1: g1 = A_hat x (half-split, XCD-claimed) ; h1 = bf16(ReLU(BN(g1 W1 + b1))*dinv)
    aggh_kernel<<<2 * NBUCK, 512, 0, stream>>>(B16, G16, srcBuck, doffG, dcntG, dinv, wcnt);
    gemm_mfma_kernel<<<gemmGrid, 256, 0, stream>>>(G16, wt, B16, nullptr, params, dinv, 1, x);
    // layer 2: g2 = A_hat h1 ; out = post(g2 @ Wfuse' + bfuse)
    aggh_kernel<<<2 * NBUCK, 512, 0, stream>>>(B16, G16, srcBuck, doffG, dcntG, dinv, wcnt + 2);
    gemm_mfma_kernel<<<gemmGrid, 256, 0, stream>>>(G16, wt + 16384, nullptr, d_out, params, dinv, 0, x);
}

// Round 10
// 379.394 us; speedup vs baseline: 3.0724x; 1.1561x over previous
//
#include <hip/hip_runtime.h>
#include <hip/hip_bf16.h>
#include <math.h>

#define N_NODES 100000
#define N_EDGES 1600000
#define F 128
#define OUT_C 64
#define NUM_CLASSES 40
#define BN_EPS 1e-5f

#define NBUCK 782   // ceil(100000/128) buckets of 128 destination nodes
#define BCAP 4096   // per-bucket edge capacity
#define FILL_BLOCKS 512
#define EPB ((N_EDGES + FILL_BLOCKS - 1) / FILL_BLOCKS)  // 3125
#define FILL_ITERS 13  // ceil(EPB/256)

// tiny folded-constant block
#define PSC 0     // [0..127]   BN scale s = rsqrt(var+eps)*gamma
#define POF 128   // [128..255] BN offset o = b1*s + beta - mean*s
#define PFB2 256  // [256..383] fused head bias

typedef __hip_bfloat16 bf16;
typedef __attribute__((ext_vector_type(8))) short bf16x8;
typedef __attribute__((ext_vector_type(4))) float f32x4;

struct ParamSegs {
    const void* src[16];  // [0]=w1 [1]=b1 [2]=w2 [3]=b2 [4]=gamma [5]=beta [6]=mean [7]=var
                          // [8]=cls_w [9]=cls_b [10]=sim_w [11]=sim_b [12]=hom_w [13]=hom_b
                          // [14]=ent_w [15]=ent_b
    int dst[16];
};

__device__ __forceinline__ float uasf(unsigned u) { return __uint_as_float(u); }
__device__ __forceinline__ unsigned f2bu(float f) {
    bf16 h = __float2bfloat16(f);
    return (unsigned)*(unsigned short*)&h;
}
__device__ __forceinline__ float ldp(const void* p, int i, int isf) {
    return isf ? ((const float*)p)[i] : __bfloat162float(((const bf16*)p)[i]);
}
__device__ __forceinline__ int load_edge(const int* __restrict__ ei, int which, int i, int i64) {
    size_t elem = (size_t)which * N_EDGES + (size_t)i;
    return i64 ? ei[elem * 2] : ei[elem];
}
__device__ __forceinline__ int detect_isf(const void* x, int t, int* sflag) {
    if (t < 64) {
        unsigned w = ((const unsigned*)x)[t];
        unsigned e = (w >> 23) & 0xFFu;
        unsigned long long m = __ballot(w == 0u || (e >= 90u && e <= 160u));
        if (t == 0) *sflag = (__popcll(m) >= 48) ? 1 : 0;
    }
    __syncthreads();
    return *sflag;
}
__device__ __forceinline__ int detect_i64(const void* ei, int t, int* sflag) {
    if (t < 64) {
        unsigned long long m = __ballot(((const unsigned*)ei)[2 * t + 1] == 0u);
        if (t == 0) *sflag = (__popcll(m) >= 60) ? 1 : 0;
    }
    __syncthreads();
    return *sflag;
}
// hoisted head-weight source for column c: pointer, base index, stride (branch OUTSIDE j-loop)
__device__ __forceinline__ void head_src(const ParamSegs& segs, int c, const void** hp, int* hb,
                                         int* hs) {
    if (c < OUT_C) {
        *hp = segs.src[8];
        *hb = c;
        *hs = OUT_C;
    } else if (c < OUT_C + NUM_CLASSES) {
        *hp = segs.src[10];
        *hb = c - OUT_C;
        *hs = NUM_CLASSES;
    } else if (c == 104) {
        *hp = segs.src[12];
        *hb = 0;
        *hs = 1;
    } else if (c == 105) {
        *hp = segs.src[14];
        *hb = 0;
        *hs = 1;
    } else {
        *hp = nullptr;
        *hb = 0;
        *hs = 0;
    }
}

#define ACC8(u)                                \
    do {                                       \
        a[0] += uasf((u).x << 16);             \
        a[1] += uasf((u).x & 0xFFFF0000u);     \
        a[2] += uasf((u).y << 16);             \
        a[3] += uasf((u).y & 0xFFFF0000u);     \
        a[4] += uasf((u).z << 16);             \
        a[5] += uasf((u).z & 0xFFFF0000u);     \
        a[6] += uasf((u).w << 16);             \
        a[7] += uasf((u).w & 0xFFFF0000u);     \
    } while (0)

// ---------------- fill: block-local LDS hist -> one reservation per (block,bucket) ----------
__global__ __launch_bounds__(256) void fill2_kernel(const int* __restrict__ ei,
                                                    int* __restrict__ bcur,
                                                    int* __restrict__ srcBuck) {
    __shared__ int hist[NBUCK];
    __shared__ int gbase[NBUCK];
    __shared__ int lcur[NBUCK];
    __shared__ int sflag;
    int blk = blockIdx.x;
    int t = threadIdx.x;
    int i64 = detect_i64(ei, t, &sflag);
    int e0 = blk * EPB;
    int ecnt = N_EDGES - e0;
    if (ecnt > EPB) ecnt = EPB;
    for (int i = t; i < NBUCK; i += 256) hist[i] = 0;
    __syncthreads();
    int ccache[FILL_ITERS];
#pragma unroll
    for (int it = 0; it < FILL_ITERS; ++it) {
        int i = t + it * 256;
        int c = -1;
        if (i < ecnt) {
            c = load_edge(ei, 1, e0 + i, i64);
            atomicAdd(&hist[c >> 7], 1);
        }
        ccache[it] = c;
    }
    __syncthreads();
    for (int i = t; i < NBUCK; i += 256) {
        int c = hist[i];
        gbase[i] = (c > 0) ? atomicAdd(&bcur[i], c) : 0;
        lcur[i] = 0;
    }
    __syncthreads();
#pragma unroll
    for (int it = 0; it < FILL_ITERS; ++it) {
        int i = t + it * 256;
        if (i < ecnt) {
            int c = ccache[it];
            int r = load_edge(ei, 0, e0 + i, i64);
            int b = c >> 7;
            int p = gbase[b] + atomicAdd(&lcur[b], 1);
            if (p < BCAP) srcBuck[b * BCAP + p] = ((c & 127) << 17) | r;
        }
    }
}

// ---------------- presort: one-time LDS counting sort per bucket, in-place ----------------
__global__ __launch_bounds__(512) void presort_kernel(int* __restrict__ srcBuck,
                                                      const int* __restrict__ bcur,
                                                      int* __restrict__ doffG,
                                                      int* __restrict__ dcntG,
                                                      float* __restrict__ dinv) {
    __shared__ int raw[BCAP];
    __shared__ int sorted[BCAP];
    __shared__ int dcnt[128], doff[128], dcur[128];
    int b = blockIdx.x;
    int t = threadIdx.x;
    int cnt = bcur[b];
    if (cnt > BCAP) cnt = BCAP;
    if (t < 128) dcnt[t] = 0;
    __syncthreads();
    for (int i = t; i < cnt; i += 512) {
        int e = srcBuck[b * BCAP + i];
        raw[i] = e;
        atomicAdd(&dcnt[e >> 17], 1);
    }
    __syncthreads();
    if (t < 128) doff[t] = dcnt[t];
    __syncthreads();
    for (int d = 1; d < 128; d <<= 1) {
        int add = 0;
        if (t < 128 && t >= d) add = doff[t - d];
        __syncthreads();
        if (t < 128) doff[t] += add;
        __syncthreads();
    }
    if (t < 128) {
        doff[t] -= dcnt[t];
        dcur[t] = 0;
    }
    __syncthreads();
    for (int i = t; i < cnt; i += 512) {
        int e = raw[i];
        int d = e >> 17;
        int r = atomicAdd(&dcur[d], 1);
        sorted[doff[d] + r] = e & 0x1FFFF;
    }
    __syncthreads();
    for (int i = t; i < cnt; i += 512) srcBuck[b * BCAP + i] = sorted[i];
    if (t < 128) {
        doffG[(b << 7) + t] = doff[t];
        dcntG[(b << 7) + t] = dcnt[t];
        int n = (b << 7) + t;
        if (n < N_NODES) dinv[n] = rsqrtf((float)(dcnt[t] + 1));
    }
}

// ---------------- cvtx + weight-prep + const-fold, ONE kernel (tail fixed) ----------------
// R9 evidence: 86us at 15% occupancy = fast cvtx + slow weight TAIL (branch-in-loop killed
// unrolling -> ~256 serialized L2-latency loads/thread; const block ran ALONE at grid end).
// Fix: (1) weight/const blocks FIRST (bid 0..128) so they overlap the 6250 cvtx blocks;
// (2) head-source branch hoisted out of the j-loop -> unrolled, ILP-pipelined loads;
// (3) cvtx uses uint4 (16B/lane), 6250 blocks cover the 1.6M items exactly.
#define WPREP_BLOCKS 129
#define CVT_BLOCKS 6250  // N_NODES*F/8 / 256
__global__ __launch_bounds__(256) void cvtxprep_kernel(const void* __restrict__ x,
                                                       ParamSegs segs,
                                                       const float* __restrict__ dinv,
                                                       unsigned short* __restrict__ B16,
                                                       float* __restrict__ params,
                                                       unsigned short* __restrict__ wt) {
    __shared__ int sflag;
    int t = threadIdx.x;
    int bid = blockIdx.x;
    int isf = detect_isf(x, t, &sflag);

    if (bid < 128) {
        int idx = bid * 256 + t;  // 0..32767
        if (idx < 16384) {
            // Wfuse[kf][c] = sum_j W2[kf][j]*HW[j][c]; store at wt2[c*128+p], p=(kf&15)*8+(kf>>4)
            int kf = idx >> 7, c = idx & 127;
            const void* hp;
            int hb, hs;
            head_src(segs, c, &hp, &hb, &hs);
            float s = 0.f;
            if (hp) {
                const void* w2 = segs.src[2];
#pragma unroll 8
                for (int j = 0; j < 128; j++) s += ldp(w2, kf * 128 + j, isf) * ldp(hp, j * hs + hb, isf);
            }
            int p = (kf & 15) * 8 + (kf >> 4);
            wt[16384 + c * 128 + p] = (unsigned short)f2bu(s);
        } else {
            // wt1[n*128+k] = W1[k][n]
            int l = idx - 16384;
            int n = l >> 7, k = l & 127;
            wt[n * 128 + k] = (unsigned short)f2bu(ldp(segs.src[0], k * 128 + n, isf));
        }
    } else if (bid == 128) {
        if (t < 128) {
            float s = rsqrtf(ldp(segs.src[7], t, isf) + BN_EPS) * ldp(segs.src[4], t, isf);
            params[PSC + t] = s;
            params[POF + t] =
                ldp(segs.src[1], t, isf) * s + ldp(segs.src[5], t, isf) - ldp(segs.src[6], t, isf) * s;
            const void* hp;
            int hb, hs;
            head_src(segs, t, &hp, &hb, &hs);
            float b = 0.f;
            if (hp) {
                const void* b2 = segs.src[3];
#pragma unroll 8
                for (int j = 0; j < 128; j++) b += ldp(b2, j, isf) * ldp(hp, j * hs + hb, isf);
            }
            if (t < OUT_C) b += ldp(segs.src[9], t, isf);
            else if (t < OUT_C + NUM_CLASSES) b += ldp(segs.src[11], t - OUT_C, isf);
            else if (t == 104) b += ldp(segs.src[13], 0, isf);
            else if (t == 105) b += ldp(segs.src[15], 0, isf);
            params[PFB2 + t] = b;
        }
    } else {
        int i8 = (bid - WPREP_BLOCKS) * 256 + t;  // exactly N_NODES*F/8 items
        int n = i8 >> 4;
        float d = dinv[n];
        float v[8];
        if (isf) {
            float4 va = ((const float4*)x)[2 * i8];
            float4 vb = ((const float4*)x)[2 * i8 + 1];
            v[0] = va.x; v[1] = va.y; v[2] = va.z; v[3] = va.w;
            v[4] = vb.x; v[5] = vb.y; v[6] = vb.z; v[7] = vb.w;
        } else {
            uint4 u = ((const uint4*)x)[i8];
            v[0] = uasf(u.x << 16);
            v[1] = uasf(u.x & 0xFFFF0000u);
            v[2] = uasf(u.y << 16);
            v[3] = uasf(u.y & 0xFFFF0000u);
            v[4] = uasf(u.z << 16);
            v[5] = uasf(u.z & 0xFFFF0000u);
            v[6] = uasf(u.w << 16);
            v[7] = uasf(u.w & 0xFFFF0000u);
        }
        uint4 o;
        o.x = f2bu(v[0] * d) | (f2bu(v[1] * d) << 16);
        o.y = f2bu(v[2] * d) | (f2bu(v[3] * d) << 16);
        o.z = f2bu(v[4] * d) | (f2bu(v[5] * d) << 16);
        o.w = f2bu(v[6] * d) | (f2bu(v[7] * d) << 16);
        ((uint4*)B16)[i8] = o;
    }
}

// ---------------- Half-feature aggregation (R6-proven: 65us, FETCH 159MB) ----------------
__global__ __launch_bounds__(512) void aggh_kernel(const unsigned short* __restrict__ IN16,
                                                   unsigned short* __restrict__ OUT16,
                                                   const int* __restrict__ srcBuck,
                                                   const int* __restrict__ doffG,
                                                   const int* __restrict__ dcntG,
                                                   const float* __restrict__ dinv,
                                                   int* __restrict__ wcnt) {
    __shared__ int sIdx[BCAP];
    __shared__ int sdoff[128], sdcnt[128];
    __shared__ int sCtl[2];
    int t = threadIdx.x;
    if (t == 0) {
        unsigned xcc;
        asm volatile("s_getreg_b32 %0, hwreg(HW_REG_XCC_ID)" : "=s"(xcc));
        int half = (xcc >> 2) & 1;
        int idx = atomicAdd(&wcnt[half], 1);
        if (idx >= NBUCK) {
            half ^= 1;
            idx = atomicAdd(&wcnt[half], 1);
        }
        sCtl[0] = idx;
        sCtl[1] = half;
    }
    __syncthreads();
    int b = sCtl[0], h = sCtl[1];
    if (b >= NBUCK) return;
    if (t < 128) {
        sdoff[t] = doffG[(b << 7) + t];
        sdcnt[t] = dcntG[(b << 7) + t];
    }
    __syncthreads();
    int cnt = sdoff[127] + sdcnt[127];
    for (int i = t; i < cnt; i += 512) sIdx[i] = srcBuck[b * BCAP + i];
    __syncthreads();

    int g8 = t >> 3;
    int hoff = h * 64 + ((t & 7) << 3);
    int base = b << 7;
    for (int d = g8; d < 128; d += 64) {
        int n = base + d;
        if (n >= N_NODES) break;
        float a[8] = {0.f, 0.f, 0.f, 0.f, 0.f, 0.f, 0.f, 0.f};
        {
            uint4 u = *(const uint4*)(IN16 + ((size_t)n << 7) + hoff);
            ACC8(u);
        }
        int o = sdoff[d], k = sdcnt[d];
        int j = 0;
        for (; j + 8 <= k; j += 8) {
            int s0 = sIdx[o + j + 0], s1 = sIdx[o + j + 1];
            int s2 = sIdx[o + j + 2], s3 = sIdx[o + j + 3];
            int s4 = sIdx[o + j + 4], s5 = sIdx[o + j + 5];
            int s6 = sIdx[o + j + 6], s7 = sIdx[o + j + 7];
            uint4 u0 = *(const uint4*)(IN16 + ((size_t)s0 << 7) + hoff);
            uint4 u1 = *(const uint4*)(IN16 + ((size_t)s1 << 7) + hoff);
            uint4 u2 = *(const uint4*)(IN16 + ((size_t)s2 << 7) + hoff);
            uint4 u3 = *(const uint4*)(IN16 + ((size_t)s3 << 7) + hoff);
            uint4 u4 = *(const uint4*)(IN16 + ((size_t)s4 << 7) + hoff);
            uint4 u5 = *(const uint4*)(IN16 + ((size_t)s5 << 7) + hoff);
            uint4 u6 = *(const uint4*)(IN16 + ((size_t)s6 << 7) + hoff);
            uint4 u7 = *(const uint4*)(IN16 + ((size_t)s7 << 7) + hoff);
            ACC8(u0);
            ACC8(u1);
            ACC8(u2);
            ACC8(u3);
            ACC8(u4);
            ACC8(u5);
            ACC8(u6);
            ACC8(u7);
        }
        for (; j + 4 <= k; j += 4) {
            int s0 = sIdx[o + j + 0], s1 = sIdx[o + j + 1];
            int s2 = sIdx[o + j + 2], s3 = sIdx[o + j + 3];
            uint4 u0 = *(const uint4*)(IN16 + ((size_t)s0 << 7) + hoff);
            uint4 u1 = *(const uint4*)(IN16 + ((size_t)s1 << 7) + hoff);
            uint4 u2 = *(const uint4*)(IN16 + ((size_t)s2 << 7) + hoff);
            uint4 u3 = *(const uint4*)(IN16 + ((size_t)s3 << 7) + hoff);
            ACC8(u0);
            ACC8(u1);
            ACC8(u2);
            ACC8(u3);
        }
        for (; j < k; j++) {
            int s0 = sIdx[o + j];
            uint4 u0 = *(const uint4*)(IN16 + ((size_t)s0 << 7) + hoff);
            ACC8(u0);
        }
        float dn = dinv[n];
        uint4 pk;
        pk.x = f2bu(a[0] * dn) | (f2bu(a[1] * dn) << 16);
        pk.y = f2bu(a[2] * dn) | (f2bu(a[3] * dn) << 16);
        pk.z = f2bu(a[4] * dn) | (f2bu(a[5] * dn) << 16);
        pk.w = f2bu(a[6] * dn) | (f2bu(a[7] * dn) << 16);
        *(uint4*)(OUT16 + ((size_t)n << 7) + hoff) = pk;
    }
}

// ---------------- MFMA GEMM (R6-proven math; consts from tiny params block) --------------
__global__ __launch_bounds__(256) void gemm_mfma_kernel(
    const unsigned short* __restrict__ A16, const unsigned short* __restrict__ Wt,
    unsigned short* __restrict__ outB, void* __restrict__ out,
    const float* __restrict__ params, const float* __restrict__ dinv, int mode,
    const void* __restrict__ x) {
    __shared__ float sF1[128], sF2[128];
    __shared__ int sflag;
    int t = threadIdx.x;
    int isf = detect_isf(x, t, &sflag);
    if (t < 128) {
        if (mode) {
            sF1[t] = params[PSC + t];
            sF2[t] = params[POF + t];
        } else {
            sF1[t] = params[PFB2 + t];
        }
    }
    __syncthreads();
    int wave = t >> 6, lane = t & 63, m16 = lane & 15, quad = lane >> 4;
    int rowbase = blockIdx.x * 64 + wave * 16;
    int rA = rowbase + m16;
    if (rA >= N_NODES) rA = N_NODES - 1;
    const size_t abase = (size_t)rA * 128 + (quad << 3);

    f32x4 acc[8];
#pragma unroll
    for (int ct = 0; ct < 8; ct++) acc[ct] = (f32x4){0.f, 0.f, 0.f, 0.f};
#pragma unroll
    for (int kk = 0; kk < 4; kk++) {
        bf16x8 af = *(const bf16x8*)(A16 + abase + kk * 32);
#pragma unroll
        for (int ct = 0; ct < 8; ct++) {
            bf16x8 bfr = *(const bf16x8*)(Wt + (size_t)((ct * 16 + m16) * 128) + kk * 32 + (quad << 3));
            acc[ct] = __builtin_amdgcn_mfma_f32_16x16x32_bf16(af, bfr, acc[ct], 0, 0, 0);
        }
    }

    int r0 = rowbase + quad * 4;
    if (mode) {
        float sc[8], of[8];
#pragma unroll
        for (int ct = 0; ct < 8; ct++) {
            sc[ct] = sF1[ct * 16 + m16];
            of[ct] = sF2[ct * 16 + m16];
        }
#pragma unroll
        for (int reg = 0; reg < 4; reg++) {
            int gr = r0 + reg;
            if (gr >= N_NODES) continue;
            float dn = dinv[gr];
            unsigned pk[4];
#pragma unroll
            for (int i = 0; i < 4; i++) {
                float v0 = fmaxf(acc[2 * i][reg] * sc[2 * i] + of[2 * i], 0.f) * dn;
                float v1 = fmaxf(acc[2 * i + 1][reg] * sc[2 * i + 1] + of[2 * i + 1], 0.f) * dn;
                pk[i] = f2bu(v0) | (f2bu(v1) << 16);
            }
            *(uint4*)(outB + (size_t)gr * 128 + (m16 << 3)) = make_uint4(pk[0], pk[1], pk[2], pk[3]);
        }
    } else {
        const size_t OFF_SIM = (size_t)N_NODES * OUT_C;
        const size_t OFF_HOM = OFF_SIM + (size_t)N_NODES * NUM_CLASSES;
        const size_t OFF_ENT = OFF_HOM + (size_t)N_NODES;
        float* outf = (float*)out;
        bf16* outb = (bf16*)out;
        float fb[8];
#pragma unroll
        for (int ct = 0; ct < 8; ct++) fb[ct] = sF1[ct * 16 + m16];
#define STORE_OUT(idx, v)                        \
    do {                                         \
        if (isf) outf[(idx)] = (v);              \
        else outb[(idx)] = __float2bfloat16(v);  \
    } while (0)
#pragma unroll
        for (int reg = 0; reg < 4; reg++) {
            int gr = r0 + reg;
            bool vrow = (gr < N_NODES);
            float v[8];
#pragma unroll
            for (int ct = 0; ct < 8; ct++) v[ct] = acc[ct][reg] + fb[ct];
            float m = fmaxf(fmaxf(v[0], v[1]), fmaxf(v[2], v[3]));
            m = fmaxf(m, __shfl_xor(m, 1));
            m = fmaxf(m, __shfl_xor(m, 2));
            m = fmaxf(m, __shfl_xor(m, 4));
            m = fmaxf(m, __shfl_xor(m, 8));
            float S = __expf(v[0] - m) + __expf(v[1] - m) + __expf(v[2] - m) + __expf(v[3] - m);
            S += __shfl_xor(S, 1);
            S += __shfl_xor(S, 2);
            S += __shfl_xor(S, 4);
            S += __shfl_xor(S, 8);
            float lS = m + __logf(S);
            if (vrow) {
#pragma unroll
                for (int ct = 0; ct < 4; ct++)
                    STORE_OUT((size_t)gr * OUT_C + ct * 16 + m16, v[ct] - lS);
            }
            bool has6 = (m16 < 8);
            float s4 = v[4], s5 = v[5], s6 = has6 ? v[6] : -INFINITY;
            float m2 = fmaxf(fmaxf(s4, s5), s6);
            m2 = fmaxf(m2, __shfl_xor(m2, 1));
            m2 = fmaxf(m2, __shfl_xor(m2, 2));
            m2 = fmaxf(m2, __shfl_xor(m2, 4));
            m2 = fmaxf(m2, __shfl_xor(m2, 8));
            float e4 = __expf(s4 - m2), e5 = __expf(s5 - m2), e6 = has6 ? __expf(s6 - m2) : 0.f;
            float S2 = e4 + e5 + e6;
            S2 += __shfl_xor(S2, 1);
            S2 += __shfl_xor(S2, 2);
            S2 += __shfl_xor(S2, 4);
            S2 += __shfl_xor(S2, 8);
            float rS2 = 1.f / S2;
            if (vrow) {
                STORE_OUT(OFF_SIM + (size_t)gr * NUM_CLASSES + m16, e4 * rS2);
                STORE_OUT(OFF_SIM + (size_t)gr * NUM_CLASSES + 16 + m16, e5 * rS2);
                if (has6) STORE_OUT(OFF_SIM + (size_t)gr * NUM_CLASSES + 32 + m16, e6 * rS2);
                if (m16 == 8) STORE_OUT(OFF_HOM + gr, 1.f / (1.f + __expf(-v[6])));
                if (m16 == 9) STORE_OUT(OFF_ENT + gr, 1.f / (1.f + __expf(-v[6])));
            }
        }
#undef STORE_OUT
    }
}

// ---------------- Launch: 8 queue items ----------------
extern "C" void kernel_launch(void* const* d_in, const int* in_sizes, int n_in,
                              void* d_out, int out_size, void* d_ws, size_t ws_size,
                              hipStream_t stream) {
    const void* x = d_in[0];
    const int* ei = (const int*)d_in[1];

    char* ws = (char*)d_ws;
    size_t o = 0;
    auto alloc = [&](size_t bytes) {
        size_t r = o;
        o = (o + bytes + 255) & ~(size_t)255;
        return r;
    };
    char* RA = ws + alloc((size_t)51 * 1024 * 1024);  // srcBuck + B16
    char* RB = ws + alloc((size_t)26 * 1024 * 1024);  // G16
    float* params = (float*)(ws + alloc(2048));
    unsigned short* wt = (unsigned short*)(ws + alloc(65536));
    float* dinv = (float*)(ws + alloc((size_t)N_NODES * 4));
    int* doffG = (int*)(ws + alloc((size_t)NBUCK * 128 * 4));
    int* dcntG = (int*)(ws + alloc((size_t)NBUCK * 128 * 4));
    int* bcur = (int*)(ws + alloc((size_t)(NBUCK + 8) * 4));
    int* wcnt = (int*)(ws + alloc(256));  // 4 counters: layer1 pair, layer2 pair

    int* srcBuck = (int*)RA;                                          // 12.81 MB
    unsigned short* B16 = (unsigned short*)(RA + 13u * 1024 * 1024);  // 25.6 MB
    unsigned short* G16 = (unsigned short*)RB;                        // 25.6 MB

    hipMemsetAsync(bcur, 0, (size_t)((char*)wcnt + 256 - (char*)bcur), stream);

    ParamSegs segs;
    const int srcIdx[16] = {2, 3, 4, 5, 6, 7, 8, 9, 10, 11, 12, 13, 14, 15, 16, 17};
    for (int k = 0; k < 16; k++) {
        segs.src[k] = d_in[srcIdx[k]];
        segs.dst[k] = 0;
    }

    fill2_kernel<<<FILL_BLOCKS, 256, 0, stream>>>(ei, bcur, srcBuck);
    presort_kernel<<<NBUCK, 512, 0, stream>>>(srcBuck, bcur, doffG, dcntG, dinv);
    cvtxprep_kernel<<<WPREP_BLOCKS + CVT_BLOCKS, 256, 0, stream>>>(x, segs, dinv, B16, params, wt);

    const int gemmGrid = (N_NODES + 63) / 64;
    // layer 1: g1 = A_hat x (half-split, XCD-claimed) ; h1 = bf16(ReLU(BN(g1 W1 + b1))*dinv)
    aggh_kernel<<<2 * NBUCK, 512, 0, stream>>>(B16, G16, srcBuck, doffG, dcntG, dinv, wcnt);
    gemm_mfma_kernel<<<gemmGrid, 256, 0, stream>>>(G16, wt, B16, nullptr, params, dinv, 1, x);
    // layer 2: g2 = A_hat h1 ; out = post(g2 @ Wfuse' + bfuse)
    aggh_kernel<<<2 * NBUCK, 512, 0, stream>>>(B16, G16, srcBuck, doffG, dcntG, dinv, wcnt + 2);
    gemm_mfma_kernel<<<gemmGrid, 256, 0, stream>>>(G16, wt + 16384, nullptr, d_out, params, dinv, 0, x);
}

// Round 12
// 374.655 us; speedup vs baseline: 3.1113x; 1.0126x over previous
//
#include <hip/hip_runtime.h>
#include <hip/hip_bf16.h>
#include <math.h>

#define N_NODES 100000
#define N_EDGES 1600000
#define F 128
#define OUT_C 64
#define NUM_CLASSES 40
#define BN_EPS 1e-5f

#define NBUCK 782   // ceil(100000/128) buckets of 128 destination nodes
#define BCAP 4096   // per-bucket edge capacity

// prep kernel grid roles
#define PREP_FILL 512
#define EPB ((N_EDGES + PREP_FILL - 1) / PREP_FILL)  // 3125
#define FILL_ITERS 13                                 // ceil(EPB/256)
#define PREP_CONST (PREP_FILL + 128)  // 640
#define PREP_CVT (PREP_FILL + 129)    // cvt blocks start at 641
#define CVT_BLOCKS 6250               // N_NODES*F/8 / 256

// tiny folded-constant block
#define PSC 0     // [0..127]   BN scale s = rsqrt(var+eps)*gamma
#define POF 128   // [128..255] BN offset o = b1*s + beta - mean*s
#define PFB2 256  // [256..383] fused head bias

typedef __hip_bfloat16 bf16;
typedef __attribute__((ext_vector_type(8))) short bf16x8;
typedef __attribute__((ext_vector_type(4))) float f32x4;

struct ParamSegs {
    const void* src[16];  // [0]=w1 [1]=b1 [2]=w2 [3]=b2 [4]=gamma [5]=beta [6]=mean [7]=var
                          // [8]=cls_w [9]=cls_b [10]=sim_w [11]=sim_b [12]=hom_w [13]=hom_b
                          // [14]=ent_w [15]=ent_b
    int dst[16];
};

__device__ __forceinline__ float uasf(unsigned u) { return __uint_as_float(u); }
__device__ __forceinline__ unsigned f2bu(float f) {
    bf16 h = __float2bfloat16(f);
    return (unsigned)*(unsigned short*)&h;
}
__device__ __forceinline__ float ldp(const void* p, int i, int isf) {
    return isf ? ((const float*)p)[i] : __bfloat162float(((const bf16*)p)[i]);
}
__device__ __forceinline__ int load_edge(const int* __restrict__ ei, int which, int i, int i64) {
    size_t elem = (size_t)which * N_EDGES + (size_t)i;
    return i64 ? ei[elem * 2] : ei[elem];
}
__device__ __forceinline__ int detect_isf(const void* x, int t, int* sflag) {
    if (t < 64) {
        unsigned w = ((const unsigned*)x)[t];
        unsigned e = (w >> 23) & 0xFFu;
        unsigned long long m = __ballot(w == 0u || (e >= 90u && e <= 160u));
        if (t == 0) *sflag = (__popcll(m) >= 48) ? 1 : 0;
    }
    __syncthreads();
    return *sflag;
}
__device__ __forceinline__ int detect_i64(const void* ei, int t, int* sflag) {
    if (t < 64) {
        unsigned long long m = __ballot(((const unsigned*)ei)[2 * t + 1] == 0u);
        if (t == 0) *sflag = (__popcll(m) >= 60) ? 1 : 0;
    }
    __syncthreads();
    return *sflag;
}
// hoisted head-weight source for column c (branch OUTSIDE the j-loop)
__device__ __forceinline__ void head_src(const ParamSegs& segs, int c, const void** hp, int* hb,
                                         int* hs) {
    if (c < OUT_C) {
        *hp = segs.src[8];
        *hb = c;
        *hs = OUT_C;
    } else if (c < OUT_C + NUM_CLASSES) {
        *hp = segs.src[10];
        *hb = c - OUT_C;
        *hs = NUM_CLASSES;
    } else if (c == 104) {
        *hp = segs.src[12];
        *hb = 0;
        *hs = 1;
    } else if (c == 105) {
        *hp = segs.src[14];
        *hb = 0;
        *hs = 1;
    } else {
        *hp = nullptr;
        *hb = 0;
        *hs = 0;
    }
}

#define ACC8(u)                                \
    do {                                       \
        a[0] += uasf((u).x << 16);             \
        a[1] += uasf((u).x & 0xFFFF0000u);     \
        a[2] += uasf((u).y << 16);             \
        a[3] += uasf((u).y & 0xFFFF0000u);     \
        a[4] += uasf((u).z << 16);             \
        a[5] += uasf((u).z & 0xFFFF0000u);     \
        a[6] += uasf((u).w << 16);             \
        a[7] += uasf((u).w & 0xFFFF0000u);     \
    } while (0)
// NOTE: 2nd macro param must NOT be named 'w' (would substitute into (u).w!)
#define ACC8W(u, s_)                                        \
    do {                                                    \
        a[0] = fmaf(uasf((u).x << 16), (s_), a[0]);         \
        a[1] = fmaf(uasf((u).x & 0xFFFF0000u), (s_), a[1]); \
        a[2] = fmaf(uasf((u).y << 16), (s_), a[2]);         \
        a[3] = fmaf(uasf((u).y & 0xFFFF0000u), (s_), a[3]); \
        a[4] = fmaf(uasf((u).z << 16), (s_), a[4]);         \
        a[5] = fmaf(uasf((u).z & 0xFFFF0000u), (s_), a[5]); \
        a[6] = fmaf(uasf((u).w << 16), (s_), a[6]);         \
        a[7] = fmaf(uasf((u).w & 0xFFFF0000u), (s_), a[7]); \
    } while (0)

// ---------------- prep: edge fill + weight prep + const fold + (f32-only) x convert ------
// R10 evidence: bench input is bf16 (absmax=0.03125 bf16-scale; harness floor_eps_k bf16
// path) -> x's layout already equals B16, so the 51MB prescale copy is pure overhead IF
// aggh-layer1 applies dinv[src] inline. cvt blocks therefore only run for f32 inputs.
// All three roles are mutually independent -> one role-split grid, one dispatch.
__global__ __launch_bounds__(256) void prep_kernel(const void* __restrict__ x,
                                                   const int* __restrict__ ei, ParamSegs segs,
                                                   int* __restrict__ bcur,
                                                   int* __restrict__ srcBuck,
                                                   float* __restrict__ params,
                                                   unsigned short* __restrict__ wt,
                                                   unsigned short* __restrict__ B16) {
    __shared__ int sflag;
    int t = threadIdx.x;
    int bid = blockIdx.x;

    if (bid < PREP_FILL) {
        // ---- edge fill (R10-identical) ----
        __shared__ int hist[NBUCK];
        __shared__ int gbase[NBUCK];
        __shared__ int lcur[NBUCK];
        int i64 = detect_i64(ei, t, &sflag);
        int e0 = bid * EPB;
        int ecnt = N_EDGES - e0;
        if (ecnt > EPB) ecnt = EPB;
        for (int i = t; i < NBUCK; i += 256) hist[i] = 0;
        __syncthreads();
        int ccache[FILL_ITERS];
#pragma unroll
        for (int it = 0; it < FILL_ITERS; ++it) {
            int i = t + it * 256;
            int c = -1;
            if (i < ecnt) {
                c = load_edge(ei, 1, e0 + i, i64);
                atomicAdd(&hist[c >> 7], 1);
            }
            ccache[it] = c;
        }
        __syncthreads();
        for (int i = t; i < NBUCK; i += 256) {
            int c = hist[i];
            gbase[i] = (c > 0) ? atomicAdd(&bcur[i], c) : 0;
            lcur[i] = 0;
        }
        __syncthreads();
#pragma unroll
        for (int it = 0; it < FILL_ITERS; ++it) {
            int i = t + it * 256;
            if (i < ecnt) {
                int c = ccache[it];
                int r = load_edge(ei, 0, e0 + i, i64);
                int b = c >> 7;
                int p = gbase[b] + atomicAdd(&lcur[b], 1);
                if (p < BCAP) srcBuck[b * BCAP + p] = ((c & 127) << 17) | r;
            }
        }
    } else if (bid < PREP_CONST) {
        // ---- weight prep (hoisted head source) ----
        int isf = detect_isf(x, t, &sflag);
        int idx = (bid - PREP_FILL) * 256 + t;  // 0..32767
        if (idx < 16384) {
            int kf = idx >> 7, c = idx & 127;
            const void* hp;
            int hb, hs;
            head_src(segs, c, &hp, &hb, &hs);
            float s = 0.f;
            if (hp) {
                const void* w2 = segs.src[2];
#pragma unroll 8
                for (int j = 0; j < 128; j++)
                    s += ldp(w2, kf * 128 + j, isf) * ldp(hp, j * hs + hb, isf);
            }
            int p = (kf & 15) * 8 + (kf >> 4);
            wt[16384 + c * 128 + p] = (unsigned short)f2bu(s);
        } else {
            int l = idx - 16384;
            int n = l >> 7, k = l & 127;
            wt[n * 128 + k] = (unsigned short)f2bu(ldp(segs.src[0], k * 128 + n, isf));
        }
    } else if (bid == PREP_CONST) {
        int isf = detect_isf(x, t, &sflag);
        if (t < 128) {
            float s = rsqrtf(ldp(segs.src[7], t, isf) + BN_EPS) * ldp(segs.src[4], t, isf);
            params[PSC + t] = s;
            params[POF + t] = ldp(segs.src[1], t, isf) * s + ldp(segs.src[5], t, isf) -
                              ldp(segs.src[6], t, isf) * s;
            const void* hp;
            int hb, hs;
            head_src(segs, t, &hp, &hb, &hs);
            float b = 0.f;
            if (hp) {
                const void* b2 = segs.src[3];
#pragma unroll 8
                for (int j = 0; j < 128; j++) b += ldp(b2, j, isf) * ldp(hp, j * hs + hb, isf);
            }
            if (t < OUT_C) b += ldp(segs.src[9], t, isf);
            else if (t < OUT_C + NUM_CLASSES) b += ldp(segs.src[11], t - OUT_C, isf);
            else if (t == 104) b += ldp(segs.src[13], 0, isf);
            else if (t == 105) b += ldp(segs.src[15], 0, isf);
            params[PFB2 + t] = b;
        }
    } else {
        // ---- x convert (UNSCALED; only needed for f32 inputs) ----
        int isf = detect_isf(x, t, &sflag);
        if (!isf) return;  // bf16 input: aggh layer-1 reads x directly
        int i8 = (bid - PREP_CVT) * 256 + t;  // exactly N_NODES*F/8 items
        float4 va = ((const float4*)x)[2 * i8];
        float4 vb = ((const float4*)x)[2 * i8 + 1];
        uint4 o;
        o.x = f2bu(va.x) | (f2bu(va.y) << 16);
        o.y = f2bu(va.z) | (f2bu(va.w) << 16);
        o.z = f2bu(vb.x) | (f2bu(vb.y) << 16);
        o.w = f2bu(vb.z) | (f2bu(vb.w) << 16);
        ((uint4*)B16)[i8] = o;
    }
}

// ---------------- presort: one-time LDS counting sort per bucket, in-place ----------------
__global__ __launch_bounds__(512) void presort_kernel(int* __restrict__ srcBuck,
                                                      const int* __restrict__ bcur,
                                                      int* __restrict__ doffG,
                                                      int* __restrict__ dcntG,
                                                      float* __restrict__ dinv) {
    __shared__ int raw[BCAP];
    __shared__ int sorted[BCAP];
    __shared__ int dcnt[128], doff[128], dcur[128];
    int b = blockIdx.x;
    int t = threadIdx.x;
    int cnt = bcur[b];
    if (cnt > BCAP) cnt = BCAP;
    if (t < 128) dcnt[t] = 0;
    __syncthreads();
    for (int i = t; i < cnt; i += 512) {
        int e = srcBuck[b * BCAP + i];
        raw[i] = e;
        atomicAdd(&dcnt[e >> 17], 1);
    }
    __syncthreads();
    if (t < 128) doff[t] = dcnt[t];
    __syncthreads();
    for (int d = 1; d < 128; d <<= 1) {
        int add = 0;
        if (t < 128 && t >= d) add = doff[t - d];
        __syncthreads();
        if (t < 128) doff[t] += add;
        __syncthreads();
    }
    if (t < 128) {
        doff[t] -= dcnt[t];
        dcur[t] = 0;
    }
    __syncthreads();
    for (int i = t; i < cnt; i += 512) {
        int e = raw[i];
        int d = e >> 17;
        int r = atomicAdd(&dcur[d], 1);
        sorted[doff[d] + r] = e & 0x1FFFF;
    }
    __syncthreads();
    for (int i = t; i < cnt; i += 512) srcBuck[b * BCAP + i] = sorted[i];
    if (t < 128) {
        doffG[(b << 7) + t] = doff[t];
        dcntG[(b << 7) + t] = dcnt[t];
        int n = (b << 7) + t;
        if (n < N_NODES) dinv[n] = rsqrtf((float)(dcnt[t] + 1));
    }
}

// ---------------- Half-feature aggregation; SRC1 = layer-1 (inline dinv[src] scale) -------
// SRC1: IN = bf16-x-direct (or B16 copy when f32); each source row scaled by dinv[src]
// via fmaf (broadcast 4B load per edge, absorbed by VALU headroom). Layer 2 (SRC1=false):
// h1 is already prescaled by gemm1's epilogue -> plain adds, IN = B16.
template <bool SRC1>
__global__ __launch_bounds__(512) void aggh_kernel(const void* __restrict__ x,
                                                   const unsigned short* __restrict__ B16,
                                                   unsigned short* __restrict__ OUT16,
                                                   const int* __restrict__ srcBuck,
                                                   const int* __restrict__ doffG,
                                                   const int* __restrict__ dcntG,
                                                   const float* __restrict__ dinv,
                                                   int* __restrict__ wcnt) {
    __shared__ int sIdx[BCAP];
    __shared__ int sdoff[128], sdcnt[128];
    __shared__ int sCtl[2];
    __shared__ int sflag;
    int t = threadIdx.x;
    const unsigned short* IN = B16;
    if (SRC1) {
        int isf = detect_isf(x, t, &sflag);
        if (!isf) IN = (const unsigned short*)x;  // bf16 input: gather straight from x
    }
    if (t == 0) {
        unsigned xcc;
        asm volatile("s_getreg_b32 %0, hwreg(HW_REG_XCC_ID)" : "=s"(xcc));
        int half = (xcc >> 2) & 1;
        int idx = atomicAdd(&wcnt[half], 1);
        if (idx >= NBUCK) {
            half ^= 1;
            idx = atomicAdd(&wcnt[half], 1);
        }
        sCtl[0] = idx;
        sCtl[1] = half;
    }
    __syncthreads();
    int b = sCtl[0], h = sCtl[1];
    if (b >= NBUCK) return;
    if (t < 128) {
        sdoff[t] = doffG[(b << 7) + t];
        sdcnt[t] = dcntG[(b << 7) + t];
    }
    __syncthreads();
    int cnt = sdoff[127] + sdcnt[127];
    for (int i = t; i < cnt; i += 512) sIdx[i] = srcBuck[b * BCAP + i];
    __syncthreads();

    int g8 = t >> 3;
    int hoff = h * 64 + ((t & 7) << 3);
    int base = b << 7;
    for (int d = g8; d < 128; d += 64) {
        int n = base + d;
        if (n >= N_NODES) break;
        float dn = dinv[n];
        float a[8] = {0.f, 0.f, 0.f, 0.f, 0.f, 0.f, 0.f, 0.f};
        {
            uint4 u = *(const uint4*)(IN + ((size_t)n << 7) + hoff);
            if (SRC1) ACC8W(u, dn);
            else ACC8(u);
        }
        int o = sdoff[d], k = sdcnt[d];
        int j = 0;
        for (; j + 8 <= k; j += 8) {
            int s0 = sIdx[o + j + 0], s1 = sIdx[o + j + 1];
            int s2 = sIdx[o + j + 2], s3 = sIdx[o + j + 3];
            int s4 = sIdx[o + j + 4], s5 = sIdx[o + j + 5];
            int s6 = sIdx[o + j + 6], s7 = sIdx[o + j + 7];
            uint4 u0 = *(const uint4*)(IN + ((size_t)s0 << 7) + hoff);
            uint4 u1 = *(const uint4*)(IN + ((size_t)s1 << 7) + hoff);
            uint4 u2 = *(const uint4*)(IN + ((size_t)s2 << 7) + hoff);
            uint4 u3 = *(const uint4*)(IN + ((size_t)s3 << 7) + hoff);
            uint4 u4 = *(const uint4*)(IN + ((size_t)s4 << 7) + hoff);
            uint4 u5 = *(const uint4*)(IN + ((size_t)s5 << 7) + hoff);
            uint4 u6 = *(const uint4*)(IN + ((size_t)s6 << 7) + hoff);
            uint4 u7 = *(const uint4*)(IN + ((size_t)s7 << 7) + hoff);
            if (SRC1) {
                float f0 = dinv[s0], f1 = dinv[s1], f2 = dinv[s2], f3 = dinv[s3];
                float f4 = dinv[s4], f5 = dinv[s5], f6 = dinv[s6], f7 = dinv[s7];
                ACC8W(u0, f0);
                ACC8W(u1, f1);
                ACC8W(u2, f2);
                ACC8W(u3, f3);
                ACC8W(u4, f4);
                ACC8W(u5, f5);
                ACC8W(u6, f6);
                ACC8W(u7, f7);
            } else {
                ACC8(u0);
                ACC8(u1);
                ACC8(u2);
                ACC8(u3);
                ACC8(u4);
                ACC8(u5);
                ACC8(u6);
                ACC8(u7);
            }
        }
        for (; j + 4 <= k; j += 4) {
            int s0 = sIdx[o + j + 0], s1 = sIdx[o + j + 1];
            int s2 = sIdx[o + j + 2], s3 = sIdx[o + j + 3];
            uint4 u0 = *(const uint4*)(IN + ((size_t)s0 << 7) + hoff);
            uint4 u1 = *(const uint4*)(IN + ((size_t)s1 << 7) + hoff);
            uint4 u2 = *(const uint4*)(IN + ((size_t)s2 << 7) + hoff);
            uint4 u3 = *(const uint4*)(IN + ((size_t)s3 << 7) + hoff);
            if (SRC1) {
                float f0 = dinv[s0], f1 = dinv[s1], f2 = dinv[s2], f3 = dinv[s3];
                ACC8W(u0, f0);
                ACC8W(u1, f1);
                ACC8W(u2, f2);
                ACC8W(u3, f3);
            } else {
                ACC8(u0);
                ACC8(u1);
                ACC8(u2);
                ACC8(u3);
            }
        }
        for (; j < k; j++) {
            int s0 = sIdx[o + j];
            uint4 u0 = *(const uint4*)(IN + ((size_t)s0 << 7) + hoff);
            if (SRC1) {
                float f0 = dinv[s0];
                ACC8W(u0, f0);
            } else {
                ACC8(u0);
            }
        }
        uint4 pk;
        pk.x = f2bu(a[0] * dn) | (f2bu(a[1] * dn) << 16);
        pk.y = f2bu(a[2] * dn) | (f2bu(a[3] * dn) << 16);
        pk.z = f2bu(a[4] * dn) | (f2bu(a[5] * dn) << 16);
        pk.w = f2bu(a[6] * dn) | (f2bu(a[7] * dn) << 16);
        *(uint4*)(OUT16 + ((size_t)n << 7) + hoff) = pk;
    }
}

// ---------------- MFMA GEMM (R6-proven math; consts from tiny params block) --------------
__global__ __launch_bounds__(256) void gemm_mfma_kernel(
    const unsigned short* __restrict__ A16, const unsigned short* __restrict__ Wt,
    unsigned short* __restrict__ outB, void* __restrict__ out,
    const float* __restrict__ params, const float* __restrict__ dinv, int mode,
    const void* __restrict__ x) {
    __shared__ float sF1[128], sF2[128];
    __shared__ int sflag;
    int t = threadIdx.x;
    int isf = detect_isf(x, t, &sflag);
    if (t < 128) {
        if (mode) {
            sF1[t] = params[PSC + t];
            sF2[t] = params[POF + t];
        } else {
            sF1[t] = params[PFB2 + t];
        }
    }
    __syncthreads();
    int wave = t >> 6, lane = t & 63, m16 = lane & 15, quad = lane >> 4;
    int rowbase = blockIdx.x * 64 + wave * 16;
    int rA = rowbase + m16;
    if (rA >= N_NODES) rA = N_NODES - 1;
    const size_t abase = (size_t)rA * 128 + (quad << 3);

    f32x4 acc[8];
#pragma unroll
    for (int ct = 0; ct < 8; ct++) acc[ct] = (f32x4){0.f, 0.f, 0.f, 0.f};
#pragma unroll
    for (int kk = 0; kk < 4; kk++) {
        bf16x8 af = *(const bf16x8*)(A16 + abase + kk * 32);
#pragma unroll
        for (int ct = 0; ct < 8; ct++) {
            bf16x8 bfr = *(const bf16x8*)(Wt + (size_t)((ct * 16 + m16) * 128) + kk * 32 + (quad << 3));
            acc[ct] = __builtin_amdgcn_mfma_f32_16x16x32_bf16(af, bfr, acc[ct], 0, 0, 0);
        }
    }

    int r0 = rowbase + quad * 4;
    if (mode) {
        float sc[8], of[8];
#pragma unroll
        for (int ct = 0; ct < 8; ct++) {
            sc[ct] = sF1[ct * 16 + m16];
            of[ct] = sF2[ct * 16 + m16];
        }
#pragma unroll
        for (int reg = 0; reg < 4; reg++) {
            int gr = r0 + reg;
            if (gr >= N_NODES) continue;
            float dn = dinv[gr];
            unsigned pk[4];
#pragma unroll
            for (int i = 0; i < 4; i++) {
                float v0 = fmaxf(acc[2 * i][reg] * sc[2 * i] + of[2 * i], 0.f) * dn;
                float v1 = fmaxf(acc[2 * i + 1][reg] * sc[2 * i + 1] + of[2 * i + 1], 0.f) * dn;
                pk[i] = f2bu(v0) | (f2bu(v1) << 16);
            }
            *(uint4*)(outB + (size_t)gr * 128 + (m16 << 3)) = make_uint4(pk[0], pk[1], pk[2], pk[3]);
        }
    } else {
        const size_t OFF_SIM = (size_t)N_NODES * OUT_C;
        const size_t OFF_HOM = OFF_SIM + (size_t)N_NODES * NUM_CLASSES;
        const size_t OFF_ENT = OFF_HOM + (size_t)N_NODES;
        float* outf = (float*)out;
        bf16* outb = (bf16*)out;
        float fb[8];
#pragma unroll
        for (int ct = 0; ct < 8; ct++) fb[ct] = sF1[ct * 16 + m16];
#define STORE_OUT(idx, v)                        \
    do {                                         \
        if (isf) outf[(idx)] = (v);              \
        else outb[(idx)] = __float2bfloat16(v);  \
    } while (0)
#pragma unroll
        for (int reg = 0; reg < 4; reg++) {
            int gr = r0 + reg;
            bool vrow = (gr < N_NODES);
            float v[8];
#pragma unroll
            for (int ct = 0; ct < 8; ct++) v[ct] = acc[ct][reg] + fb[ct];
            float m = fmaxf(fmaxf(v[0], v[1]), fmaxf(v[2], v[3]));
            m = fmaxf(m, __shfl_xor(m, 1));
            m = fmaxf(m, __shfl_xor(m, 2));
            m = fmaxf(m, __shfl_xor(m, 4));
            m = fmaxf(m, __shfl_xor(m, 8));
            float S = __expf(v[0] - m) + __expf(v[1] - m) + __expf(v[2] - m) + __expf(v[3] - m);
            S += __shfl_xor(S, 1);
            S += __shfl_xor(S, 2);
            S += __shfl_xor(S, 4);
            S += __shfl_xor(S, 8);
            float lS = m + __logf(S);
            if (vrow) {
#pragma unroll
                for (int ct = 0; ct < 4; ct++)
                    STORE_OUT((size_t)gr * OUT_C + ct * 16 + m16, v[ct] - lS);
            }
            bool has6 = (m16 < 8);
            float s4 = v[4], s5 = v[5], s6 = has6 ? v[6] : -INFINITY;
            float m2 = fmaxf(fmaxf(s4, s5), s6);
            m2 = fmaxf(m2, __shfl_xor(m2, 1));
            m2 = fmaxf(m2, __shfl_xor(m2, 2));
            m2 = fmaxf(m2, __shfl_xor(m2, 4));
            m2 = fmaxf(m2, __shfl_xor(m2, 8));
            float e4 = __expf(s4 - m2), e5 = __expf(s5 - m2), e6 = has6 ? __expf(s6 - m2) : 0.f;
            float S2 = e4 + e5 + e6;
            S2 += __shfl_xor(S2, 1);
            S2 += __shfl_xor(S2, 2);
            S2 += __shfl_xor(S2, 4);
            S2 += __shfl_xor(S2, 8);
            float rS2 = 1.f / S2;
            if (vrow) {
                STORE_OUT(OFF_SIM + (size_t)gr * NUM_CLASSES + m16, e4 * rS2);
                STORE_OUT(OFF_SIM + (size_t)gr * NUM_CLASSES + 16 + m16, e5 * rS2);
                if (has6) STORE_OUT(OFF_SIM + (size_t)gr * NUM_CLASSES + 32 + m16, e6 * rS2);
                if (m16 == 8) STORE_OUT(OFF_HOM + gr, 1.f / (1.f + __expf(-v[6])));
                if (m16 == 9) STORE_OUT(OFF_ENT + gr, 1.f / (1.f + __expf(-v[6])));
            }
        }
#undef STORE_OUT
    }
}

// ---------------- Launch: memset + 6 kernels ----------------
extern "C" void kernel_launch(void* const* d_in, const int* in_sizes, int n_in,
                              void* d_out, int out_size, void* d_ws, size_t ws_size,
                              hipStream_t stream) {
    const void* x = d_in[0];
    const int* ei = (const int*)d_in[1];

    char* ws = (char*)d_ws;
    size_t o = 0;
    auto alloc = [&](size_t bytes) {
        size_t r = o;
        o = (o + bytes + 255) & ~(size_t)255;
        return r;
    };
    char* RA = ws + alloc((size_t)51 * 1024 * 1024);  // srcBuck + B16
    char* RB = ws + alloc((size_t)26 * 1024 * 1024);  // G16
    float* params = (float*)(ws + alloc(2048));
    unsigned short* wt = (unsigned short*)(ws + alloc(65536));
    float* dinv = (float*)(ws + alloc((size_t)N_NODES * 4));
    int* doffG = (int*)(ws + alloc((size_t)NBUCK * 128 * 4));
    int* dcntG = (int*)(ws + alloc((size_t)NBUCK * 128 * 4));
    int* bcur = (int*)(ws + alloc((size_t)(NBUCK + 8) * 4));
    int* wcnt = (int*)(ws + alloc(256));  // 4 counters: layer1 pair, layer2 pair

    int* srcBuck = (int*)RA;                                          // 12.81 MB
    unsigned short* B16 = (unsigned short*)(RA + 13u * 1024 * 1024);  // 25.6 MB
    unsigned short* G16 = (unsigned short*)RB;                        // 25.6 MB

    hipMemsetAsync(bcur, 0, (size_t)((char*)wcnt + 256 - (char*)bcur), stream);

    ParamSegs segs;
    const int srcIdx[16] = {2, 3, 4, 5, 6, 7, 8, 9, 10, 11, 12, 13, 14, 15, 16, 17};
    for (int k = 0; k < 16; k++) {
        segs.src[k] = d_in[srcIdx[k]];
        segs.dst[k] = 0;
    }

    prep_kernel<<<PREP_CVT + CVT_BLOCKS, 256, 0, stream>>>(x, ei, segs, bcur, srcBuck, params,
                                                           wt, B16);
    presort_kernel<<<NBUCK, 512, 0, stream>>>(srcBuck, bcur, doffG, dcntG, dinv);

    const int gemmGrid = (N_NODES + 63) / 64;
    // layer 1: g1 = A_hat x (bf16-x-direct, dinv[src] inline) -> G16; h1 -> B16
    aggh_kernel<true><<<2 * NBUCK, 512, 0, stream>>>(x, B16, G16, srcBuck, doffG, dcntG, dinv,
                                                     wcnt);
    gemm_mfma_kernel<<<gemmGrid, 256, 0, stream>>>(G16, wt, B16, nullptr, params, dinv, 1, x);
    // layer 2: g2 = A_hat h1 -> G16 ; out = post(g2 @ Wfuse' + bfuse)
    aggh_kernel<false><<<2 * NBUCK, 512, 0, stream>>>(x, B16, G16, srcBuck, doffG, dcntG, dinv,
                                                      wcnt + 2);
    gemm_mfma_kernel<<<gemmGrid, 256, 0, stream>>>(G16, wt + 16384, nullptr, d_out, params, dinv,
                                                   0, x);
}